// Round 10
// baseline (257.958 us; speedup 1.0000x reference)
//
#include <hip/hip_runtime.h>
#include <math.h>

// Problem constants (B=8, C=192, H=W=32)
#define BB 8
#define CC 192
#define LL 1024
#define RT 8192         // total rows = BB*LL
#define DI 384          // d_inner
#define DT_RANK 12
#define NS 16           // D_STATE
#define NSEG 16
#define SEGL 64

typedef __attribute__((ext_vector_type(8))) short bf16x8;   // 8 bf16 (4 VGPRs)
typedef __attribute__((ext_vector_type(4))) float f32x4;

// RNE float->bf16 and back, manual (no header dependency)
__device__ __forceinline__ unsigned short f2bf(float f) {
    unsigned u = __float_as_uint(f);
    unsigned r = (u + 0x7FFFu + ((u >> 16) & 1u)) >> 16;
    return (unsigned short)r;
}
__device__ __forceinline__ float bf2f(unsigned short h) {
    return __uint_as_float(((unsigned)h) << 16);
}

// ---------------------------------------------------------------------------
// DPP butterfly sum across a row of 16 lanes (lanes 16k..16k+15).
__device__ __forceinline__ float row_sum16(float v) {
    v += __int_as_float(__builtin_amdgcn_update_dpp(0, __float_as_int(v), 0x140, 0xF, 0xF, true));
    v += __int_as_float(__builtin_amdgcn_update_dpp(0, __float_as_int(v), 0x141, 0xF, 0xF, true));
    v += __int_as_float(__builtin_amdgcn_update_dpp(0, __float_as_int(v), 0x4E,  0xF, 0xF, true));
    v += __int_as_float(__builtin_amdgcn_update_dpp(0, __float_as_int(v), 0xB1,  0xF, 0xF, true));
    return v;
}

// ---------------------------------------------------------------------------
// K1: W2[j,c'] = sum_c in_proj_w[j,c]*proj_w[c,c'], emitted as SPLIT bf16
// planes W2hi/W2lo (w = hi + lo) for the MFMA gemm_xz. Also splits out_w
// into owhi/owlo planes. bias2[j] = in_proj_w[j,:]·proj_b. Zero-inits xdT.
__global__ void fuse_w_kernel(const float* __restrict__ in_proj_w,
                              const float* __restrict__ proj_w,
                              const float* __restrict__ proj_b,
                              const float* __restrict__ out_w,
                              unsigned short* __restrict__ W2hi,
                              unsigned short* __restrict__ W2lo,
                              unsigned short* __restrict__ owhi,
                              unsigned short* __restrict__ owlo,
                              float* __restrict__ bias2,
                              float* __restrict__ xdT) {
    int j = blockIdx.x;
    int cp = threadIdx.x;
    int gtid = j * CC + cp;                       // 0..147455
    for (int i = gtid; i < 44 * RT; i += 768 * CC) xdT[i] = 0.f;
    if (j < DI) {
        float v = out_w[cp * DI + j];
        unsigned short h = f2bf(v);
        owhi[cp * DI + j] = h;
        owlo[cp * DI + j] = f2bf(v - bf2f(h));
    }
    __shared__ float wrow[CC];
    wrow[cp] = in_proj_w[j * CC + cp];
    __syncthreads();
    float acc = 0.f;
#pragma unroll 4
    for (int c = 0; c < CC; ++c) acc = fmaf(wrow[c], proj_w[c * CC + cp], acc);
    unsigned short h = f2bf(acc);
    W2hi[j * CC + cp] = h;
    W2lo[j * CC + cp] = f2bf(acc - bf2f(h));
    if (cp == 0) {
        float b = 0.f;
        for (int c = 0; c < CC; ++c) b = fmaf(wrow[c], proj_b[c], b);
        bias2[j] = b;
    }
}

// ---------------------------------------------------------------------------
// K2: xzT[j, row] = sum_c x[b,c,l]*W2[j,c] + bias2[j]  via split-bf16 MFMA.
// D = Whi*Xhi + Whi*Xlo + Wlo*Xhi (3x mfma_f32_16x16x32_bf16), ~2^-18 rel.
// (R7-proven.) grid (128,12), 256 thr, 8KB LDS.
__global__ __launch_bounds__(256) void gemm_xz(const float* __restrict__ x,
                                               const unsigned short* __restrict__ W2hi,
                                               const unsigned short* __restrict__ W2lo,
                                               const float* __restrict__ bias2,
                                               float* __restrict__ xzT) {
    __shared__ unsigned short xhi[2048];   // [kb][col][e] 4KB
    __shared__ unsigned short xlo[2048];
    int r0 = blockIdx.x * 64;
    int j0 = blockIdx.y * 64;
    int b  = r0 >> 10;
    int l0 = r0 & 1023;
    int tid = threadIdx.x;
    int lane = tid & 63;
    int wid = tid >> 6;          // wave id = staging kb
    int jw = j0 + wid * 16;
    const float* xb = x + b * CC * LL + l0 + lane;   // staging col = lane
    f32x4 z4 = {0.f, 0.f, 0.f, 0.f};
    f32x4 acc[4] = {z4, z4, z4, z4};
    int arow = jw + (lane & 15);           // A fragment row (j)
    int akb  = (lane >> 4) * 8;            // A fragment k sub-block
    for (int ks = 0; ks < 6; ++ks) {
        int k0 = ks * 32;
        float v[8];
#pragma unroll
        for (int e = 0; e < 8; ++e) v[e] = xb[(k0 + wid * 8 + e) * LL];
        union U8 { unsigned short u[8]; bf16x8 v8; } hv, lv;
#pragma unroll
        for (int e = 0; e < 8; ++e) {
            unsigned short h = f2bf(v[e]);
            hv.u[e] = h;
            lv.u[e] = f2bf(v[e] - bf2f(h));
        }
        *(bf16x8*)&xhi[(wid * 64 + lane) * 8] = hv.v8;
        *(bf16x8*)&xlo[(wid * 64 + lane) * 8] = lv.v8;
        __syncthreads();
        int aoff = arow * CC + k0 + akb;
        bf16x8 ah = *(const bf16x8*)&W2hi[aoff];
        bf16x8 al = *(const bf16x8*)&W2lo[aoff];
#pragma unroll
        for (int rt = 0; rt < 4; ++rt) {
            int boff = ((lane >> 4) * 64 + rt * 16 + (lane & 15)) * 8;
            bf16x8 bh = *(const bf16x8*)&xhi[boff];
            bf16x8 bl = *(const bf16x8*)&xlo[boff];
            acc[rt] = __builtin_amdgcn_mfma_f32_16x16x32_bf16(ah, bh, acc[rt], 0, 0, 0);
            acc[rt] = __builtin_amdgcn_mfma_f32_16x16x32_bf16(ah, bl, acc[rt], 0, 0, 0);
            acc[rt] = __builtin_amdgcn_mfma_f32_16x16x32_bf16(al, bh, acc[rt], 0, 0, 0);
        }
        __syncthreads();
    }
    bool is_z = (j0 >= DI);
#pragma unroll
    for (int rt = 0; rt < 4; ++rt) {
        int rbase = r0 + rt * 16 + (lane & 15);
#pragma unroll
        for (int reg = 0; reg < 4; ++reg) {
            int j = jw + (lane >> 4) * 4 + reg;
            float o = acc[rt][reg] + bias2[j];
            if (is_z) o = __fdividef(o, 1.f + __expf(-o));
            xzT[j * RT + rbase] = o;
        }
    }
}

// ---------------------------------------------------------------------------
// K3: skinny GEMM with fused causal depthwise conv (k=4) + silu in staging.
// K-split: blockIdx.y picks channel range [y*192, y*192+192); partial sums
// via atomicAdd into pre-zeroed xdT (2 contributors -> deterministic).
__global__ __launch_bounds__(512) void xproj_conv_gemm(const float* __restrict__ xzT,
                                                       const float* __restrict__ conv_w,
                                                       const float* __restrict__ conv_b,
                                                       const float* __restrict__ aw,
                                                       float* __restrict__ xcT,
                                                       float* __restrict__ xdT) {
    __shared__ float Bs[32][64];
    int col0 = blockIdx.x * 64;
    int kbase = blockIdx.y * 192;
    int tid = threadIdx.x;
    int col = tid & 63, mg = tid >> 6;          // mg wave-uniform -> scalar A loads
    int mb = mg * 6;                             // rows mb..mb+5 (44..47 discarded)
    const float* ar[6];
#pragma unroll
    for (int m = 0; m < 6; ++m) ar[m] = aw + min(mb + m, 43) * DI + kbase;
    float acc[6] = {};
    int ks = tid >> 4, c4 = (tid & 15) * 4;
    bool atL0 = ((col0 & 1023) == 0) && (c4 == 0);   // conv zero-pad boundary
    for (int k0 = 0; k0 < 192; k0 += 32) {
        int dch = kbase + k0 + ks;
        const float* src = xzT + (size_t)dch * RT + col0 + c4;
        float4 cur = *(const float4*)src;
        float4 prev = make_float4(0.f, 0.f, 0.f, 0.f);
        if (!atL0) prev = *(const float4*)(src - 4);
        float4 w4 = *(const float4*)&conv_w[dch * 4];   // w0=x w1=y w2=z w3=w
        float bb = conv_b[dch];
        float v0 = bb + w4.w * cur.x + w4.z * prev.w + w4.y * prev.z + w4.x * prev.y;
        float v1 = bb + w4.w * cur.y + w4.z * cur.x  + w4.y * prev.w + w4.x * prev.z;
        float v2 = bb + w4.w * cur.z + w4.z * cur.y  + w4.y * cur.x  + w4.x * prev.w;
        float v3 = bb + w4.w * cur.w + w4.z * cur.z  + w4.y * cur.y  + w4.x * cur.x;
        float4 o;
        o.x = __fdividef(v0, 1.f + __expf(-v0));
        o.y = __fdividef(v1, 1.f + __expf(-v1));
        o.z = __fdividef(v2, 1.f + __expf(-v2));
        o.w = __fdividef(v3, 1.f + __expf(-v3));
        *(float4*)&Bs[ks][c4] = o;
        *(float4*)&xcT[(size_t)dch * RT + col0 + c4] = o;   // own channel range
        __syncthreads();
#pragma unroll
        for (int k = 0; k < 32; ++k) {
            float bv = Bs[k][col];
#pragma unroll
            for (int m = 0; m < 6; ++m)
                acc[m] = fmaf(ar[m][k0 + k], bv, acc[m]);
        }
        __syncthreads();
    }
#pragma unroll
    for (int m = 0; m < 6; ++m)
        if (mb + m < 44)
            atomicAdd(&xdT[(mb + m) * RT + col0 + col], acc[m]);
}

// ---------------------------------------------------------------------------
// K3b (R10): dt/g precompute. dtT[d][row] = softplus(dtr[.]·dtw[d,.] + dtb[d]),
// gT[d][row] = dtT·xcT[d][row]. Same fmaf order as the old in-scan compute ->
// bitwise-identical. Hoisting this out makes both scan passes LDS-free and
// barrier-free. grid (32, 24), 256 thr.
__global__ __launch_bounds__(256) void dt_g_kernel(const float* __restrict__ xdT,
                                                   const float* __restrict__ xcT,
                                                   const float* __restrict__ dtw,
                                                   const float* __restrict__ dtb,
                                                   float* __restrict__ dtT,
                                                   float* __restrict__ gT) {
    __shared__ float dtw_s[192];
    __shared__ float dtb_s[16];
    int tid = threadIdx.x;
    int row = blockIdx.x * 256 + tid;
    int d0 = blockIdx.y * 16;
    if (tid < 192) dtw_s[tid] = dtw[d0 * DT_RANK + tid];
    if (tid < 16)  dtb_s[tid] = dtb[d0 + tid];
    __syncthreads();
    float dtr[DT_RANK];
#pragma unroll
    for (int rr = 0; rr < DT_RANK; ++rr) dtr[rr] = xdT[rr * RT + row];
#pragma unroll
    for (int dd = 0; dd < 16; ++dd) {
        int d = d0 + dd;
        float acc = dtb_s[dd];
#pragma unroll
        for (int rr = 0; rr < DT_RANK; ++rr)
            acc = fmaf(dtr[rr], dtw_s[dd * DT_RANK + rr], acc);
        float dtv = fmaxf(acc, 0.f) + __logf(1.f + __expf(-fabsf(acc)));
        dtT[(size_t)d * RT + row] = dtv;
        gT[(size_t)d * RT + row]  = dtv * xcT[(size_t)d * RT + row];
    }
}

// ---------------------------------------------------------------------------
// K4a (R10): per-segment scan from h=0 — LDS-FREE, BARRIER-FREE. Thread
// (dl,n) reads dt/g (row d) and B (row 12+n) as contiguous float4 from
// L2-hot global. Emits P = exp(a*sum(dt)), Hf = final h.
// grid (16 seg, 24 dblk, 8 b), block 256.
__global__ __launch_bounds__(256) void scan_part1(const float* __restrict__ dtT,
                                                  const float* __restrict__ gT,
                                                  const float* __restrict__ xdT,
                                                  const float* __restrict__ A_log,
                                                  float* __restrict__ P,
                                                  float* __restrict__ Hf) {
    int seg = blockIdx.x, d0 = blockIdx.y * 16, b = blockIdx.z;
    int row0 = b * LL + seg * SEGL;
    int tid = threadIdx.x;
    int lane = tid & 63;
    int n = lane & 15;
    int dl = ((tid >> 6) << 2) | (lane >> 4);
    int d = d0 + dl;
    float a = -__expf(A_log[d * NS + n]);
    float h = 0.f, sdt = 0.f;
    for (int ch = 0; ch < 4; ++ch) {
        int r = row0 + ch * 16;
        const float4* dt4 = (const float4*)&dtT[(size_t)d * RT + r];
        const float4* g4p = (const float4*)&gT[(size_t)d * RT + r];
        const float4* b4p = (const float4*)&xdT[(size_t)(12 + n) * RT + r];
        float dv[16], gb[16];
#pragma unroll
        for (int q = 0; q < 4; ++q) {
            float4 d4 = dt4[q];
            float4 g4 = g4p[q];
            float4 b4 = b4p[q];
            dv[q * 4 + 0] = d4.x; dv[q * 4 + 1] = d4.y;
            dv[q * 4 + 2] = d4.z; dv[q * 4 + 3] = d4.w;
            gb[q * 4 + 0] = g4.x * b4.x; gb[q * 4 + 1] = g4.y * b4.y;
            gb[q * 4 + 2] = g4.z * b4.z; gb[q * 4 + 3] = g4.w * b4.w;
        }
        float eh[16];
#pragma unroll
        for (int i = 0; i < 16; ++i) eh[i] = __expf(dv[i] * a);
#pragma unroll
        for (int i = 0; i < 16; ++i) {
            sdt += dv[i];
            h = fmaf(eh[i], h, gb[i]);
        }
    }
    int idx = ((seg * BB + b) * DI + d) * NS + n;
    P[idx] = __expf(a * sdt);
    Hf[idx] = h;
}

// ---------------------------------------------------------------------------
// K4b (R10): rescan each segment from folded h_init — LDS-FREE, BARRIER-FREE.
// dt/g/B/C via direct float4 global loads; DPP row-of-16 butterfly for the
// n-reduction; lane n keeps step i==n (y-writer role (dl,n)).
__global__ __launch_bounds__(256) void scan_part2(const float* __restrict__ dtT,
                                                  const float* __restrict__ gT,
                                                  const float* __restrict__ xdT,
                                                  const float* __restrict__ xcT,
                                                  const float* __restrict__ zsT,
                                                  const float* __restrict__ P,
                                                  const float* __restrict__ Hf,
                                                  const float* __restrict__ A_log,
                                                  const float* __restrict__ Dp,
                                                  float* __restrict__ yT) {
    int seg = blockIdx.x, d0 = blockIdx.y * 16, b = blockIdx.z;
    int row0 = b * LL + seg * SEGL;
    int tid = threadIdx.x;
    int lane = tid & 63;
    int n = lane & 15;
    int dl = ((tid >> 6) << 2) | (lane >> 4);
    int d = d0 + dl;
    float a = -__expf(A_log[d * NS + n]);
    float Dpd = Dp[d];
    // h_init: fold earlier segments' summaries (coalesced loads)
    float h = 0.f;
    for (int s = 0; s < seg; ++s) {
        int off = ((s * BB + b) * DI + d) * NS + n;
        h = fmaf(P[off], h, Hf[off]);
    }
    for (int ch = 0; ch < 4; ++ch) {
        int r = row0 + ch * 16;
        const float4* dt4 = (const float4*)&dtT[(size_t)d * RT + r];
        const float4* g4p = (const float4*)&gT[(size_t)d * RT + r];
        const float4* b4p = (const float4*)&xdT[(size_t)(12 + n) * RT + r];
        const float4* c4p = (const float4*)&xdT[(size_t)(28 + n) * RT + r];
        float xr = xcT[(size_t)d * RT + r + n];
        float zr = zsT[(size_t)d * RT + r + n];
        float dv[16], gb[16], cv[16];
#pragma unroll
        for (int q = 0; q < 4; ++q) {
            float4 d4 = dt4[q];
            float4 g4 = g4p[q];
            float4 b4 = b4p[q];
            float4 c4 = c4p[q];
            dv[q * 4 + 0] = d4.x; dv[q * 4 + 1] = d4.y;
            dv[q * 4 + 2] = d4.z; dv[q * 4 + 3] = d4.w;
            gb[q * 4 + 0] = g4.x * b4.x; gb[q * 4 + 1] = g4.y * b4.y;
            gb[q * 4 + 2] = g4.z * b4.z; gb[q * 4 + 3] = g4.w * b4.w;
            cv[q * 4 + 0] = c4.x; cv[q * 4 + 1] = c4.y;
            cv[q * 4 + 2] = c4.z; cv[q * 4 + 3] = c4.w;
        }
        float eh[16];
#pragma unroll
        for (int i = 0; i < 16; ++i) eh[i] = __expf(dv[i] * a);
        float yacc = 0.f;
#pragma unroll
        for (int i = 0; i < 16; ++i) {
            h = fmaf(eh[i], h, gb[i]);
            float v = row_sum16(h * cv[i]);   // sum over n within the 16-lane row
            yacc = (n == i) ? v : yacc;       // lane n keeps step i==n
        }
        yT[(size_t)d * RT + r + n] = fmaf(xr, Dpd, yacc) * zr;
    }
}

// ---------------------------------------------------------------------------
// K5: out[b, c, l] = sum_d yT[d, row] * out_w[c, d]  via split-bf16 MFMA.
// (R8-proven.) grid (128, 3), 256 thr, 8KB LDS.
__global__ __launch_bounds__(256) void gemm_out(const float* __restrict__ yT,
                                                const unsigned short* __restrict__ owhi,
                                                const unsigned short* __restrict__ owlo,
                                                float* __restrict__ out) {
    __shared__ unsigned short yhi[2048];   // [kb][col][e] 4KB
    __shared__ unsigned short ylo[2048];
    int r0 = blockIdx.x * 64;
    int c0 = blockIdx.y * 64;
    int b  = r0 >> 10;
    int l0 = r0 & 1023;
    int tid = threadIdx.x;
    int lane = tid & 63;
    int wid = tid >> 6;          // wave id = staging kb
    int cw = c0 + wid * 16;
    const float* yb = yT + r0 + lane;      // staging col = lane
    f32x4 z4 = {0.f, 0.f, 0.f, 0.f};
    f32x4 acc[4] = {z4, z4, z4, z4};
    int arow = cw + (lane & 15);           // A fragment row (c)
    int akb  = (lane >> 4) * 8;            // A fragment k sub-block
    for (int ks = 0; ks < 12; ++ks) {
        int k0 = ks * 32;
        float v[8];
#pragma unroll
        for (int e = 0; e < 8; ++e) v[e] = yb[(size_t)(k0 + wid * 8 + e) * RT];
        union U8 { unsigned short u[8]; bf16x8 v8; } hv, lv;
#pragma unroll
        for (int e = 0; e < 8; ++e) {
            unsigned short h = f2bf(v[e]);
            hv.u[e] = h;
            lv.u[e] = f2bf(v[e] - bf2f(h));
        }
        *(bf16x8*)&yhi[(wid * 64 + lane) * 8] = hv.v8;
        *(bf16x8*)&ylo[(wid * 64 + lane) * 8] = lv.v8;
        __syncthreads();
        int aoff = arow * DI + k0 + akb;
        bf16x8 ah = *(const bf16x8*)&owhi[aoff];
        bf16x8 al = *(const bf16x8*)&owlo[aoff];
#pragma unroll
        for (int rt = 0; rt < 4; ++rt) {
            int boff = ((lane >> 4) * 64 + rt * 16 + (lane & 15)) * 8;
            bf16x8 bh = *(const bf16x8*)&yhi[boff];
            bf16x8 bl = *(const bf16x8*)&ylo[boff];
            acc[rt] = __builtin_amdgcn_mfma_f32_16x16x32_bf16(ah, bh, acc[rt], 0, 0, 0);
            acc[rt] = __builtin_amdgcn_mfma_f32_16x16x32_bf16(ah, bl, acc[rt], 0, 0, 0);
            acc[rt] = __builtin_amdgcn_mfma_f32_16x16x32_bf16(al, bh, acc[rt], 0, 0, 0);
        }
        __syncthreads();
    }
    float* ob = out + b * CC * LL;
#pragma unroll
    for (int rt = 0; rt < 4; ++rt) {
        int lbase = l0 + rt * 16 + (lane & 15);
#pragma unroll
        for (int reg = 0; reg < 4; ++reg) {
            int c = cw + (lane >> 4) * 4 + reg;
            ob[c * LL + lbase] = acc[rt][reg];
        }
    }
}

// ---------------------------------------------------------------------------
extern "C" void kernel_launch(void* const* d_in, const int* in_sizes, int n_in,
                              void* d_out, int out_size, void* d_ws, size_t ws_size,
                              hipStream_t stream) {
    const float* x         = (const float*)d_in[0];
    const float* proj_w    = (const float*)d_in[1];
    const float* proj_b    = (const float*)d_in[2];
    const float* in_proj_w = (const float*)d_in[3];
    const float* conv_w    = (const float*)d_in[4];
    const float* conv_b    = (const float*)d_in[5];
    const float* xproj_w   = (const float*)d_in[6];
    const float* dtproj_w  = (const float*)d_in[7];
    const float* dtproj_b  = (const float*)d_in[8];
    const float* A_log     = (const float*)d_in[9];
    const float* Dp        = (const float*)d_in[10];
    const float* out_w     = (const float*)d_in[11];
    float* out = (float*)d_out;

    float* ws    = (float*)d_ws;
    unsigned short* W2hi = (unsigned short*)ws;          // 147456 bf16 = 73728 f32 slots
    unsigned short* W2lo = (unsigned short*)(ws + 73728);
    float* bias2 = ws + 147456;           // 768
    float* xzT   = bias2 + 768;           // 768*8192 = 6291456 (x raw, z silu'd)
    float* xcT   = xzT + 6291456;         // 3145728
    float* yT    = xcT + 3145728;         // 3145728
    float* xdT   = yT + 3145728;          // 44*8192 = 360448 (0-11 dtr, 12-27 B, 28-43 C)
    unsigned short* owhi = (unsigned short*)(xdT + 360448);      // 73728 bf16
    unsigned short* owlo = (unsigned short*)(xdT + 360448 + 36864);
    float* dtT   = xdT + 360448 + 73728;  // 3145728
    float* gT    = dtT + 3145728;         // 3145728
    float* P     = gT + 3145728;          // 786432
    float* Hf    = P + 786432;            // 786432
    float* zsT   = xzT + DI * RT;         // z half, silu applied by gemm_xz epilogue

    fuse_w_kernel<<<768, 192, 0, stream>>>(in_proj_w, proj_w, proj_b, out_w,
                                           W2hi, W2lo, owhi, owlo, bias2, xdT);
    gemm_xz<<<dim3(128, 12), 256, 0, stream>>>(x, W2hi, W2lo, bias2, xzT);
    xproj_conv_gemm<<<dim3(128, 2), 512, 0, stream>>>(xzT, conv_w, conv_b,
                                                      xproj_w, xcT, xdT);
    dt_g_kernel<<<dim3(32, 24), 256, 0, stream>>>(xdT, xcT, dtproj_w, dtproj_b,
                                                  dtT, gT);
    scan_part1<<<dim3(16, 24, 8), 256, 0, stream>>>(dtT, gT, xdT, A_log, P, Hf);
    scan_part2<<<dim3(16, 24, 8), 256, 0, stream>>>(dtT, gT, xdT, xcT, zsT,
                                                    P, Hf, A_log, Dp, yT);
    gemm_out<<<dim3(128, 3), 256, 0, stream>>>(yT, owhi, owlo, out);
}

// Round 11
// 200.317 us; speedup vs baseline: 1.2877x; 1.2877x over previous
//
#include <hip/hip_runtime.h>
#include <math.h>

// Problem constants (B=8, C=192, H=W=32)
#define BB 8
#define CC 192
#define LL 1024
#define RT 8192         // total rows = BB*LL
#define DI 384          // d_inner
#define DT_RANK 12
#define NS 16           // D_STATE
#define NSEG 16
#define SEGL 64

typedef __attribute__((ext_vector_type(8))) short bf16x8;   // 8 bf16 (4 VGPRs)
typedef __attribute__((ext_vector_type(4))) float f32x4;

// RNE float->bf16 and back, manual (no header dependency)
__device__ __forceinline__ unsigned short f2bf(float f) {
    unsigned u = __float_as_uint(f);
    unsigned r = (u + 0x7FFFu + ((u >> 16) & 1u)) >> 16;
    return (unsigned short)r;
}
__device__ __forceinline__ float bf2f(unsigned short h) {
    return __uint_as_float(((unsigned)h) << 16);
}

// ---------------------------------------------------------------------------
// DPP butterfly sum across a row of 16 lanes (lanes 16k..16k+15).
__device__ __forceinline__ float row_sum16(float v) {
    v += __int_as_float(__builtin_amdgcn_update_dpp(0, __float_as_int(v), 0x140, 0xF, 0xF, true));
    v += __int_as_float(__builtin_amdgcn_update_dpp(0, __float_as_int(v), 0x141, 0xF, 0xF, true));
    v += __int_as_float(__builtin_amdgcn_update_dpp(0, __float_as_int(v), 0x4E,  0xF, 0xF, true));
    v += __int_as_float(__builtin_amdgcn_update_dpp(0, __float_as_int(v), 0xB1,  0xF, 0xF, true));
    return v;
}

// ---------------------------------------------------------------------------
// K1: W2[j,c'] = sum_c in_proj_w[j,c]*proj_w[c,c'], emitted as SPLIT bf16
// planes W2hi/W2lo (w = hi + lo) for the MFMA gemm_xz. Also splits out_w
// into owhi/owlo planes. bias2[j] = in_proj_w[j,:]·proj_b. Zero-inits xdT.
__global__ void fuse_w_kernel(const float* __restrict__ in_proj_w,
                              const float* __restrict__ proj_w,
                              const float* __restrict__ proj_b,
                              const float* __restrict__ out_w,
                              unsigned short* __restrict__ W2hi,
                              unsigned short* __restrict__ W2lo,
                              unsigned short* __restrict__ owhi,
                              unsigned short* __restrict__ owlo,
                              float* __restrict__ bias2,
                              float* __restrict__ xdT) {
    int j = blockIdx.x;
    int cp = threadIdx.x;
    int gtid = j * CC + cp;                       // 0..147455
    for (int i = gtid; i < 44 * RT; i += 768 * CC) xdT[i] = 0.f;
    if (j < DI) {
        float v = out_w[cp * DI + j];
        unsigned short h = f2bf(v);
        owhi[cp * DI + j] = h;
        owlo[cp * DI + j] = f2bf(v - bf2f(h));
    }
    __shared__ float wrow[CC];
    wrow[cp] = in_proj_w[j * CC + cp];
    __syncthreads();
    float acc = 0.f;
#pragma unroll 4
    for (int c = 0; c < CC; ++c) acc = fmaf(wrow[c], proj_w[c * CC + cp], acc);
    unsigned short h = f2bf(acc);
    W2hi[j * CC + cp] = h;
    W2lo[j * CC + cp] = f2bf(acc - bf2f(h));
    if (cp == 0) {
        float b = 0.f;
        for (int c = 0; c < CC; ++c) b = fmaf(wrow[c], proj_b[c], b);
        bias2[j] = b;
    }
}

// ---------------------------------------------------------------------------
// K2: xzT[j, row] = sum_c x[b,c,l]*W2[j,c] + bias2[j]  via split-bf16 MFMA.
// D = Whi*Xhi + Whi*Xlo + Wlo*Xhi (3x mfma_f32_16x16x32_bf16), ~2^-18 rel.
// (R7-proven.) grid (128,12), 256 thr, 8KB LDS.
__global__ __launch_bounds__(256) void gemm_xz(const float* __restrict__ x,
                                               const unsigned short* __restrict__ W2hi,
                                               const unsigned short* __restrict__ W2lo,
                                               const float* __restrict__ bias2,
                                               float* __restrict__ xzT) {
    __shared__ unsigned short xhi[2048];   // [kb][col][e] 4KB
    __shared__ unsigned short xlo[2048];
    int r0 = blockIdx.x * 64;
    int j0 = blockIdx.y * 64;
    int b  = r0 >> 10;
    int l0 = r0 & 1023;
    int tid = threadIdx.x;
    int lane = tid & 63;
    int wid = tid >> 6;          // wave id = staging kb
    int jw = j0 + wid * 16;
    const float* xb = x + b * CC * LL + l0 + lane;   // staging col = lane
    f32x4 z4 = {0.f, 0.f, 0.f, 0.f};
    f32x4 acc[4] = {z4, z4, z4, z4};
    int arow = jw + (lane & 15);           // A fragment row (j)
    int akb  = (lane >> 4) * 8;            // A fragment k sub-block
    for (int ks = 0; ks < 6; ++ks) {
        int k0 = ks * 32;
        float v[8];
#pragma unroll
        for (int e = 0; e < 8; ++e) v[e] = xb[(k0 + wid * 8 + e) * LL];
        union U8 { unsigned short u[8]; bf16x8 v8; } hv, lv;
#pragma unroll
        for (int e = 0; e < 8; ++e) {
            unsigned short h = f2bf(v[e]);
            hv.u[e] = h;
            lv.u[e] = f2bf(v[e] - bf2f(h));
        }
        *(bf16x8*)&xhi[(wid * 64 + lane) * 8] = hv.v8;
        *(bf16x8*)&xlo[(wid * 64 + lane) * 8] = lv.v8;
        __syncthreads();
        int aoff = arow * CC + k0 + akb;
        bf16x8 ah = *(const bf16x8*)&W2hi[aoff];
        bf16x8 al = *(const bf16x8*)&W2lo[aoff];
#pragma unroll
        for (int rt = 0; rt < 4; ++rt) {
            int boff = ((lane >> 4) * 64 + rt * 16 + (lane & 15)) * 8;
            bf16x8 bh = *(const bf16x8*)&xhi[boff];
            bf16x8 bl = *(const bf16x8*)&xlo[boff];
            acc[rt] = __builtin_amdgcn_mfma_f32_16x16x32_bf16(ah, bh, acc[rt], 0, 0, 0);
            acc[rt] = __builtin_amdgcn_mfma_f32_16x16x32_bf16(ah, bl, acc[rt], 0, 0, 0);
            acc[rt] = __builtin_amdgcn_mfma_f32_16x16x32_bf16(al, bh, acc[rt], 0, 0, 0);
        }
        __syncthreads();
    }
    bool is_z = (j0 >= DI);
#pragma unroll
    for (int rt = 0; rt < 4; ++rt) {
        int rbase = r0 + rt * 16 + (lane & 15);
#pragma unroll
        for (int reg = 0; reg < 4; ++reg) {
            int j = jw + (lane >> 4) * 4 + reg;
            float o = acc[rt][reg] + bias2[j];
            if (is_z) o = __fdividef(o, 1.f + __expf(-o));
            xzT[j * RT + rbase] = o;
        }
    }
}

// ---------------------------------------------------------------------------
// K3: skinny GEMM with fused causal depthwise conv (k=4) + silu in staging.
// R11: FOUR-way K-split (was 2). blockIdx.y picks channel range
// [y*96, y*96+96): 512 blocks = 2 blocks/CU = 16 waves/CU (was 1 block/CU,
// latency-exposed at every barrier). Staging and xzT reads still done once
// per channel; xcT writes partitioned; partial sums via atomicAdd into
// pre-zeroed xdT (4 contributors, order-independent to fp rounding).
// grid (128,4), 512 thr.
__global__ __launch_bounds__(512) void xproj_conv_gemm(const float* __restrict__ xzT,
                                                       const float* __restrict__ conv_w,
                                                       const float* __restrict__ conv_b,
                                                       const float* __restrict__ aw,
                                                       float* __restrict__ xcT,
                                                       float* __restrict__ xdT) {
    __shared__ float Bs[32][64];
    int col0 = blockIdx.x * 64;
    int kbase = blockIdx.y * 96;
    int tid = threadIdx.x;
    int col = tid & 63, mg = tid >> 6;          // mg wave-uniform -> scalar A loads
    int mb = mg * 6;                             // rows mb..mb+5 (44..47 discarded)
    const float* ar[6];
#pragma unroll
    for (int m = 0; m < 6; ++m) ar[m] = aw + min(mb + m, 43) * DI + kbase;
    float acc[6] = {};
    int ks = tid >> 4, c4 = (tid & 15) * 4;
    bool atL0 = ((col0 & 1023) == 0) && (c4 == 0);   // conv zero-pad boundary
    for (int k0 = 0; k0 < 96; k0 += 32) {
        int dch = kbase + k0 + ks;
        const float* src = xzT + (size_t)dch * RT + col0 + c4;
        float4 cur = *(const float4*)src;
        float4 prev = make_float4(0.f, 0.f, 0.f, 0.f);
        if (!atL0) prev = *(const float4*)(src - 4);
        float4 w4 = *(const float4*)&conv_w[dch * 4];   // w0=x w1=y w2=z w3=w
        float bb = conv_b[dch];
        float v0 = bb + w4.w * cur.x + w4.z * prev.w + w4.y * prev.z + w4.x * prev.y;
        float v1 = bb + w4.w * cur.y + w4.z * cur.x  + w4.y * prev.w + w4.x * prev.z;
        float v2 = bb + w4.w * cur.z + w4.z * cur.y  + w4.y * cur.x  + w4.x * prev.w;
        float v3 = bb + w4.w * cur.w + w4.z * cur.z  + w4.y * cur.y  + w4.x * cur.x;
        float4 o;
        o.x = __fdividef(v0, 1.f + __expf(-v0));
        o.y = __fdividef(v1, 1.f + __expf(-v1));
        o.z = __fdividef(v2, 1.f + __expf(-v2));
        o.w = __fdividef(v3, 1.f + __expf(-v3));
        *(float4*)&Bs[ks][c4] = o;
        *(float4*)&xcT[(size_t)dch * RT + col0 + c4] = o;   // own channel range
        __syncthreads();
#pragma unroll
        for (int k = 0; k < 32; ++k) {
            float bv = Bs[k][col];
#pragma unroll
            for (int m = 0; m < 6; ++m)
                acc[m] = fmaf(ar[m][k0 + k], bv, acc[m]);
        }
        __syncthreads();
    }
#pragma unroll
    for (int m = 0; m < 6; ++m)
        if (mb + m < 44)
            atomicAdd(&xdT[(mb + m) * RT + col0 + col], acc[m]);
}

// ---------------------------------------------------------------------------
// K4a: per-segment scan from h=0; dt computed inline from dtr rows of xdT.
// Emits P = exp(a*sum(dt)) (== prod(dA)), Hf = final h.
// grid (16 seg, 24 dblk, 8 b), block 256.  (R8-proven version, reverted.)
__global__ __launch_bounds__(256) void scan_part1(const float* __restrict__ xdT,
                                                  const float* __restrict__ xcT,
                                                  const float* __restrict__ dtw,
                                                  const float* __restrict__ dtb,
                                                  const float* __restrict__ A_log,
                                                  float* __restrict__ P,
                                                  float* __restrict__ Hf) {
    __shared__ float dt_s[16][20], g_s[16][20], B_s[16][20];
    __shared__ float dtr_s[12][17];
    __shared__ float dtw_s[192];
    __shared__ float dtb_s[16];
    int seg = blockIdx.x, d0 = blockIdx.y * 16, b = blockIdx.z;
    int row0 = b * LL + seg * SEGL;
    int tid = threadIdx.x;
    int lane = tid & 63;
    int n = lane & 15;
    int dl = ((tid >> 6) << 2) | (lane >> 4);
    int tdd = tid >> 4, ti = tid & 15;
    if (tid < 192) dtw_s[tid] = dtw[d0 * DT_RANK + tid];
    if (tid < 16)  dtb_s[tid] = dtb[d0 + tid];
    float a = -__expf(A_log[(d0 + dl) * NS + n]);
    float h = 0.f, sdt = 0.f;
    for (int ch = 0; ch < 4; ++ch) {
        int r = row0 + ch * 16;
        float xv = xcT[(d0 + tdd) * RT + r + ti];
        B_s[tdd][ti] = xdT[(12 + tdd) * RT + r + ti];
        if (tid < 192) dtr_s[tid >> 4][ti] = xdT[(tid >> 4) * RT + r + ti];
        __syncthreads();     // staging ready (prev chunk's preloads done)
        float acc = dtb_s[tdd];
#pragma unroll
        for (int rr = 0; rr < DT_RANK; ++rr)
            acc = fmaf(dtr_s[rr][ti], dtw_s[tdd * DT_RANK + rr], acc);
        float dtv = fmaxf(acc, 0.f) + __logf(1.f + __expf(-fabsf(acc)));
        dt_s[tdd][ti] = dtv;
        g_s[tdd][ti]  = dtv * xv;
        __syncthreads();     // dt_s/g_s ready
        float dv[16], gb[16];
#pragma unroll
        for (int q = 0; q < 4; ++q) {
            float4 d4 = *(const float4*)&dt_s[dl][q * 4];   // broadcast within row
            float4 g4 = *(const float4*)&g_s[dl][q * 4];
            float4 b4 = *(const float4*)&B_s[n][q * 4];
            dv[q * 4 + 0] = d4.x; dv[q * 4 + 1] = d4.y;
            dv[q * 4 + 2] = d4.z; dv[q * 4 + 3] = d4.w;
            gb[q * 4 + 0] = g4.x * b4.x; gb[q * 4 + 1] = g4.y * b4.y;
            gb[q * 4 + 2] = g4.z * b4.z; gb[q * 4 + 3] = g4.w * b4.w;
        }
        __syncthreads();     // preload done -> next chunk may overwrite LDS
        float eh[16];
#pragma unroll
        for (int i = 0; i < 16; ++i) eh[i] = __expf(dv[i] * a);
#pragma unroll
        for (int i = 0; i < 16; ++i) {
            sdt += dv[i];
            h = fmaf(eh[i], h, gb[i]);
        }
    }
    int idx = ((seg * BB + b) * DI + d0 + dl) * NS + n;
    P[idx] = __expf(a * sdt);
    Hf[idx] = h;
}

// ---------------------------------------------------------------------------
// K4b: rescan each segment; h_init computed in-block by folding the earlier
// segments' (P,Hf) summaries. DPP row-of-16 butterfly for the n-reduction.
// (R8-proven version, reverted.)
__global__ __launch_bounds__(256) void scan_part2(const float* __restrict__ xdT,
                                                  const float* __restrict__ xcT,
                                                  const float* __restrict__ zsT,
                                                  const float* __restrict__ dtw,
                                                  const float* __restrict__ dtb,
                                                  const float* __restrict__ P,
                                                  const float* __restrict__ Hf,
                                                  const float* __restrict__ A_log,
                                                  const float* __restrict__ Dp,
                                                  float* __restrict__ yT) {
    __shared__ float dt_s[16][20], g_s[16][20], B_s[16][20], C_s[16][20];
    __shared__ float dtr_s[12][17];
    __shared__ float dtw_s[192];
    __shared__ float dtb_s[16];
    int seg = blockIdx.x, d0 = blockIdx.y * 16, b = blockIdx.z;
    int row0 = b * LL + seg * SEGL;
    int tid = threadIdx.x;
    int lane = tid & 63;
    int n = lane & 15;
    int dl = ((tid >> 6) << 2) | (lane >> 4);
    int d = d0 + dl;
    int tdd = tid >> 4, ti = tid & 15;
    if (tid < 192) dtw_s[tid] = dtw[d0 * DT_RANK + tid];
    if (tid < 16)  dtb_s[tid] = dtb[d0 + tid];
    float a = -__expf(A_log[d * NS + n]);
    float Dpd = Dp[d];
    // h_init: fold earlier segments' summaries (coalesced loads)
    float h = 0.f;
    for (int s = 0; s < seg; ++s) {
        int off = ((s * BB + b) * DI + d) * NS + n;
        h = fmaf(P[off], h, Hf[off]);
    }
    for (int ch = 0; ch < 4; ++ch) {
        int r = row0 + ch * 16;
        // epilogue operands for the (dl,n) writer role (L1/L2-resident)
        float xr = xcT[(size_t)d * RT + r + n];
        float zr = zsT[(size_t)d * RT + r + n];
        // staging role (tdd,ti)
        float xv = xcT[(d0 + tdd) * RT + r + ti];
        B_s[tdd][ti] = xdT[(12 + tdd) * RT + r + ti];
        C_s[tdd][ti] = xdT[(28 + tdd) * RT + r + ti];
        if (tid < 192) dtr_s[tid >> 4][ti] = xdT[(tid >> 4) * RT + r + ti];
        __syncthreads();     // staging ready
        float acc = dtb_s[tdd];
#pragma unroll
        for (int rr = 0; rr < DT_RANK; ++rr)
            acc = fmaf(dtr_s[rr][ti], dtw_s[tdd * DT_RANK + rr], acc);
        float dtv = fmaxf(acc, 0.f) + __logf(1.f + __expf(-fabsf(acc)));
        dt_s[tdd][ti] = dtv;
        g_s[tdd][ti]  = dtv * xv;
        __syncthreads();     // dt_s/g_s ready
        float dv[16], gb[16], cv[16];
#pragma unroll
        for (int q = 0; q < 4; ++q) {
            float4 d4 = *(const float4*)&dt_s[dl][q * 4];
            float4 g4 = *(const float4*)&g_s[dl][q * 4];
            float4 b4 = *(const float4*)&B_s[n][q * 4];
            float4 c4 = *(const float4*)&C_s[n][q * 4];
            dv[q * 4 + 0] = d4.x; dv[q * 4 + 1] = d4.y;
            dv[q * 4 + 2] = d4.z; dv[q * 4 + 3] = d4.w;
            gb[q * 4 + 0] = g4.x * b4.x; gb[q * 4 + 1] = g4.y * b4.y;
            gb[q * 4 + 2] = g4.z * b4.z; gb[q * 4 + 3] = g4.w * b4.w;
            cv[q * 4 + 0] = c4.x; cv[q * 4 + 1] = c4.y;
            cv[q * 4 + 2] = c4.z; cv[q * 4 + 3] = c4.w;
        }
        __syncthreads();     // preload done -> next chunk may overwrite LDS
        float eh[16];
#pragma unroll
        for (int i = 0; i < 16; ++i) eh[i] = __expf(dv[i] * a);
        float yacc = 0.f;
#pragma unroll
        for (int i = 0; i < 16; ++i) {
            h = fmaf(eh[i], h, gb[i]);
            float v = row_sum16(h * cv[i]);   // sum over n within the 16-lane row
            yacc = (n == i) ? v : yacc;       // lane n keeps step i==n
        }
        yT[(size_t)d * RT + r + n] = fmaf(xr, Dpd, yacc) * zr;
    }
}

// ---------------------------------------------------------------------------
// K5: out[b, c, l] = sum_d yT[d, row] * out_w[c, d]  via split-bf16 MFMA.
// (R8-proven.) grid (128, 3), 256 thr, 8KB LDS.
__global__ __launch_bounds__(256) void gemm_out(const float* __restrict__ yT,
                                                const unsigned short* __restrict__ owhi,
                                                const unsigned short* __restrict__ owlo,
                                                float* __restrict__ out) {
    __shared__ unsigned short yhi[2048];   // [kb][col][e] 4KB
    __shared__ unsigned short ylo[2048];
    int r0 = blockIdx.x * 64;
    int c0 = blockIdx.y * 64;
    int b  = r0 >> 10;
    int l0 = r0 & 1023;
    int tid = threadIdx.x;
    int lane = tid & 63;
    int wid = tid >> 6;          // wave id = staging kb
    int cw = c0 + wid * 16;
    const float* yb = yT + r0 + lane;      // staging col = lane
    f32x4 z4 = {0.f, 0.f, 0.f, 0.f};
    f32x4 acc[4] = {z4, z4, z4, z4};
    int arow = cw + (lane & 15);           // A fragment row (c)
    int akb  = (lane >> 4) * 8;            // A fragment k sub-block
    for (int ks = 0; ks < 12; ++ks) {
        int k0 = ks * 32;
        float v[8];
#pragma unroll
        for (int e = 0; e < 8; ++e) v[e] = yb[(size_t)(k0 + wid * 8 + e) * RT];
        union U8 { unsigned short u[8]; bf16x8 v8; } hv, lv;
#pragma unroll
        for (int e = 0; e < 8; ++e) {
            unsigned short h = f2bf(v[e]);
            hv.u[e] = h;
            lv.u[e] = f2bf(v[e] - bf2f(h));
        }
        *(bf16x8*)&yhi[(wid * 64 + lane) * 8] = hv.v8;
        *(bf16x8*)&ylo[(wid * 64 + lane) * 8] = lv.v8;
        __syncthreads();
        int aoff = arow * DI + k0 + akb;
        bf16x8 ah = *(const bf16x8*)&owhi[aoff];
        bf16x8 al = *(const bf16x8*)&owlo[aoff];
#pragma unroll
        for (int rt = 0; rt < 4; ++rt) {
            int boff = ((lane >> 4) * 64 + rt * 16 + (lane & 15)) * 8;
            bf16x8 bh = *(const bf16x8*)&yhi[boff];
            bf16x8 bl = *(const bf16x8*)&ylo[boff];
            acc[rt] = __builtin_amdgcn_mfma_f32_16x16x32_bf16(ah, bh, acc[rt], 0, 0, 0);
            acc[rt] = __builtin_amdgcn_mfma_f32_16x16x32_bf16(ah, bl, acc[rt], 0, 0, 0);
            acc[rt] = __builtin_amdgcn_mfma_f32_16x16x32_bf16(al, bh, acc[rt], 0, 0, 0);
        }
        __syncthreads();
    }
    float* ob = out + b * CC * LL;
#pragma unroll
    for (int rt = 0; rt < 4; ++rt) {
        int lbase = l0 + rt * 16 + (lane & 15);
#pragma unroll
        for (int reg = 0; reg < 4; ++reg) {
            int c = cw + (lane >> 4) * 4 + reg;
            ob[c * LL + lbase] = acc[rt][reg];
        }
    }
}

// ---------------------------------------------------------------------------
extern "C" void kernel_launch(void* const* d_in, const int* in_sizes, int n_in,
                              void* d_out, int out_size, void* d_ws, size_t ws_size,
                              hipStream_t stream) {
    const float* x         = (const float*)d_in[0];
    const float* proj_w    = (const float*)d_in[1];
    const float* proj_b    = (const float*)d_in[2];
    const float* in_proj_w = (const float*)d_in[3];
    const float* conv_w    = (const float*)d_in[4];
    const float* conv_b    = (const float*)d_in[5];
    const float* xproj_w   = (const float*)d_in[6];
    const float* dtproj_w  = (const float*)d_in[7];
    const float* dtproj_b  = (const float*)d_in[8];
    const float* A_log     = (const float*)d_in[9];
    const float* Dp        = (const float*)d_in[10];
    const float* out_w     = (const float*)d_in[11];
    float* out = (float*)d_out;

    float* ws    = (float*)d_ws;
    unsigned short* W2hi = (unsigned short*)ws;          // 147456 bf16 = 73728 f32 slots
    unsigned short* W2lo = (unsigned short*)(ws + 73728);
    float* bias2 = ws + 147456;           // 768
    float* xzT   = bias2 + 768;           // 768*8192 = 6291456 (x raw, z silu'd)
    float* xcT   = xzT + 6291456;         // 3145728
    float* yT    = xcT + 3145728;         // 3145728
    float* xdT   = yT + 3145728;          // 44*8192 = 360448 (0-11 dtr, 12-27 B, 28-43 C)
    float* P     = xdT + 360448;          // 786432
    float* Hf    = P + 786432;            // 786432
    unsigned short* owhi = (unsigned short*)(Hf + 786432);       // 73728 bf16
    unsigned short* owlo = (unsigned short*)(Hf + 786432 + 36864);
    float* zsT   = xzT + DI * RT;         // z half, silu applied by gemm_xz epilogue

    fuse_w_kernel<<<768, 192, 0, stream>>>(in_proj_w, proj_w, proj_b, out_w,
                                           W2hi, W2lo, owhi, owlo, bias2, xdT);
    gemm_xz<<<dim3(128, 12), 256, 0, stream>>>(x, W2hi, W2lo, bias2, xzT);
    xproj_conv_gemm<<<dim3(128, 4), 512, 0, stream>>>(xzT, conv_w, conv_b,
                                                      xproj_w, xcT, xdT);
    scan_part1<<<dim3(16, 24, 8), 256, 0, stream>>>(xdT, xcT, dtproj_w, dtproj_b,
                                                    A_log, P, Hf);
    scan_part2<<<dim3(16, 24, 8), 256, 0, stream>>>(xdT, xcT, zsT, dtproj_w, dtproj_b,
                                                    P, Hf, A_log, Dp, yT);
    gemm_out<<<dim3(128, 3), 256, 0, stream>>>(yT, owhi, owlo, out);
}

// Round 12
// 197.200 us; speedup vs baseline: 1.3081x; 1.0158x over previous
//
#include <hip/hip_runtime.h>
#include <math.h>

// Problem constants (B=8, C=192, H=W=32)
#define BB 8
#define CC 192
#define LL 1024
#define RT 8192         // total rows = BB*LL
#define DI 384          // d_inner
#define DT_RANK 12
#define NS 16           // D_STATE
#define NSEG 16
#define SEGL 64

typedef __attribute__((ext_vector_type(8))) short bf16x8;   // 8 bf16 (4 VGPRs)
typedef __attribute__((ext_vector_type(4))) float f32x4;

// RNE float->bf16 and back, manual (no header dependency)
__device__ __forceinline__ unsigned short f2bf(float f) {
    unsigned u = __float_as_uint(f);
    unsigned r = (u + 0x7FFFu + ((u >> 16) & 1u)) >> 16;
    return (unsigned short)r;
}
__device__ __forceinline__ float bf2f(unsigned short h) {
    return __uint_as_float(((unsigned)h) << 16);
}

// row-level DPP shuffle (16-lane rows), compile-time ctrl
#define DPPF(v, ctrl) __int_as_float(__builtin_amdgcn_update_dpp(0, __float_as_int(v), ctrl, 0xF, 0xF, true))

// ---------------------------------------------------------------------------
// K1: W2[j,c'] = sum_c in_proj_w[j,c]*proj_w[c,c'], emitted as SPLIT bf16
// planes W2hi/W2lo (w = hi + lo) for the MFMA gemm_xz. Also splits out_w
// into owhi/owlo planes. bias2[j] = in_proj_w[j,:]·proj_b. Zero-inits xdT.
__global__ void fuse_w_kernel(const float* __restrict__ in_proj_w,
                              const float* __restrict__ proj_w,
                              const float* __restrict__ proj_b,
                              const float* __restrict__ out_w,
                              unsigned short* __restrict__ W2hi,
                              unsigned short* __restrict__ W2lo,
                              unsigned short* __restrict__ owhi,
                              unsigned short* __restrict__ owlo,
                              float* __restrict__ bias2,
                              float* __restrict__ xdT) {
    int j = blockIdx.x;
    int cp = threadIdx.x;
    int gtid = j * CC + cp;                       // 0..147455
    for (int i = gtid; i < 44 * RT; i += 768 * CC) xdT[i] = 0.f;
    if (j < DI) {
        float v = out_w[cp * DI + j];
        unsigned short h = f2bf(v);
        owhi[cp * DI + j] = h;
        owlo[cp * DI + j] = f2bf(v - bf2f(h));
    }
    __shared__ float wrow[CC];
    wrow[cp] = in_proj_w[j * CC + cp];
    __syncthreads();
    float acc = 0.f;
#pragma unroll 4
    for (int c = 0; c < CC; ++c) acc = fmaf(wrow[c], proj_w[c * CC + cp], acc);
    unsigned short h = f2bf(acc);
    W2hi[j * CC + cp] = h;
    W2lo[j * CC + cp] = f2bf(acc - bf2f(h));
    if (cp == 0) {
        float b = 0.f;
        for (int c = 0; c < CC; ++c) b = fmaf(wrow[c], proj_b[c], b);
        bias2[j] = b;
    }
}

// ---------------------------------------------------------------------------
// K2: xzT[j, row] = sum_c x[b,c,l]*W2[j,c] + bias2[j]  via split-bf16 MFMA.
// D = Whi*Xhi + Whi*Xlo + Wlo*Xhi (3x mfma_f32_16x16x32_bf16), ~2^-18 rel.
// R12: j-tile widened 64->128 (wave owns TWO j-subtiles jw, jw+64 sharing
// the same staged B fragments) -> x is re-read by 6 j-tiles instead of 12,
// halving L3 traffic (151->75 MB). grid (128,6), 256 thr, 8KB LDS.
__global__ __launch_bounds__(256) void gemm_xz(const float* __restrict__ x,
                                               const unsigned short* __restrict__ W2hi,
                                               const unsigned short* __restrict__ W2lo,
                                               const float* __restrict__ bias2,
                                               float* __restrict__ xzT) {
    __shared__ unsigned short xhi[2048];   // [kb][col][e] 4KB
    __shared__ unsigned short xlo[2048];
    int r0 = blockIdx.x * 64;
    int j0 = blockIdx.y * 128;
    int b  = r0 >> 10;
    int l0 = r0 & 1023;
    int tid = threadIdx.x;
    int lane = tid & 63;
    int wid = tid >> 6;          // wave id = staging kb
    int jw = j0 + wid * 16;      // sub-tile 0; sub-tile 1 at +64
    const float* xb = x + b * CC * LL + l0 + lane;   // staging col = lane
    f32x4 z4 = {0.f, 0.f, 0.f, 0.f};
    f32x4 acc[2][4] = {{z4, z4, z4, z4}, {z4, z4, z4, z4}};
    int arow = lane & 15;                  // A fragment row offset (j)
    int akb  = (lane >> 4) * 8;            // A fragment k sub-block
    for (int ks = 0; ks < 6; ++ks) {
        int k0 = ks * 32;
        // ---- stage x[k0+kb*8+e][l0+col] -> hi/lo bf16 in frag order
        float v[8];
#pragma unroll
        for (int e = 0; e < 8; ++e) v[e] = xb[(k0 + wid * 8 + e) * LL];
        union U8 { unsigned short u[8]; bf16x8 v8; } hv, lv;
#pragma unroll
        for (int e = 0; e < 8; ++e) {
            unsigned short h = f2bf(v[e]);
            hv.u[e] = h;
            lv.u[e] = f2bf(v[e] - bf2f(h));
        }
        *(bf16x8*)&xhi[(wid * 64 + lane) * 8] = hv.v8;
        *(bf16x8*)&xlo[(wid * 64 + lane) * 8] = lv.v8;
        __syncthreads();
        // ---- A fragments (hi/lo) for both j-subtiles
        int aoff0 = (jw + arow) * CC + k0 + akb;
        int aoff1 = aoff0 + 64 * CC;
        bf16x8 ah0 = *(const bf16x8*)&W2hi[aoff0];
        bf16x8 al0 = *(const bf16x8*)&W2lo[aoff0];
        bf16x8 ah1 = *(const bf16x8*)&W2hi[aoff1];
        bf16x8 al1 = *(const bf16x8*)&W2lo[aoff1];
        // ---- 4 row sub-tiles x 2 j-subtiles x 3 split-mfma
#pragma unroll
        for (int rt = 0; rt < 4; ++rt) {
            int boff = ((lane >> 4) * 64 + rt * 16 + (lane & 15)) * 8;
            bf16x8 bh = *(const bf16x8*)&xhi[boff];
            bf16x8 bl = *(const bf16x8*)&xlo[boff];
            acc[0][rt] = __builtin_amdgcn_mfma_f32_16x16x32_bf16(ah0, bh, acc[0][rt], 0, 0, 0);
            acc[0][rt] = __builtin_amdgcn_mfma_f32_16x16x32_bf16(ah0, bl, acc[0][rt], 0, 0, 0);
            acc[0][rt] = __builtin_amdgcn_mfma_f32_16x16x32_bf16(al0, bh, acc[0][rt], 0, 0, 0);
            acc[1][rt] = __builtin_amdgcn_mfma_f32_16x16x32_bf16(ah1, bh, acc[1][rt], 0, 0, 0);
            acc[1][rt] = __builtin_amdgcn_mfma_f32_16x16x32_bf16(ah1, bl, acc[1][rt], 0, 0, 0);
            acc[1][rt] = __builtin_amdgcn_mfma_f32_16x16x32_bf16(al1, bh, acc[1][rt], 0, 0, 0);
        }
        __syncthreads();
    }
    bool is_z = (j0 >= DI);   // j0 in {0,128,256,384,512,640}; DI=384=3*128
#pragma unroll
    for (int js = 0; js < 2; ++js) {
#pragma unroll
        for (int rt = 0; rt < 4; ++rt) {
            int rbase = r0 + rt * 16 + (lane & 15);
#pragma unroll
            for (int reg = 0; reg < 4; ++reg) {
                int j = jw + js * 64 + (lane >> 4) * 4 + reg;
                float o = acc[js][rt][reg] + bias2[j];
                if (is_z) o = __fdividef(o, 1.f + __expf(-o));
                xzT[j * RT + rbase] = o;
            }
        }
    }
}

// ---------------------------------------------------------------------------
// K3: skinny GEMM with fused causal depthwise conv (k=4) + silu in staging.
// 4-way K-split (R11-proven). grid (128,4), 512 thr.
__global__ __launch_bounds__(512) void xproj_conv_gemm(const float* __restrict__ xzT,
                                                       const float* __restrict__ conv_w,
                                                       const float* __restrict__ conv_b,
                                                       const float* __restrict__ aw,
                                                       float* __restrict__ xcT,
                                                       float* __restrict__ xdT) {
    __shared__ float Bs[32][64];
    int col0 = blockIdx.x * 64;
    int kbase = blockIdx.y * 96;
    int tid = threadIdx.x;
    int col = tid & 63, mg = tid >> 6;          // mg wave-uniform -> scalar A loads
    int mb = mg * 6;                             // rows mb..mb+5 (44..47 discarded)
    const float* ar[6];
#pragma unroll
    for (int m = 0; m < 6; ++m) ar[m] = aw + min(mb + m, 43) * DI + kbase;
    float acc[6] = {};
    int ks = tid >> 4, c4 = (tid & 15) * 4;
    bool atL0 = ((col0 & 1023) == 0) && (c4 == 0);   // conv zero-pad boundary
    for (int k0 = 0; k0 < 96; k0 += 32) {
        int dch = kbase + k0 + ks;
        const float* src = xzT + (size_t)dch * RT + col0 + c4;
        float4 cur = *(const float4*)src;
        float4 prev = make_float4(0.f, 0.f, 0.f, 0.f);
        if (!atL0) prev = *(const float4*)(src - 4);
        float4 w4 = *(const float4*)&conv_w[dch * 4];   // w0=x w1=y w2=z w3=w
        float bb = conv_b[dch];
        float v0 = bb + w4.w * cur.x + w4.z * prev.w + w4.y * prev.z + w4.x * prev.y;
        float v1 = bb + w4.w * cur.y + w4.z * cur.x  + w4.y * prev.w + w4.x * prev.z;
        float v2 = bb + w4.w * cur.z + w4.z * cur.y  + w4.y * cur.x  + w4.x * prev.w;
        float v3 = bb + w4.w * cur.w + w4.z * cur.z  + w4.y * cur.y  + w4.x * cur.x;
        float4 o;
        o.x = __fdividef(v0, 1.f + __expf(-v0));
        o.y = __fdividef(v1, 1.f + __expf(-v1));
        o.z = __fdividef(v2, 1.f + __expf(-v2));
        o.w = __fdividef(v3, 1.f + __expf(-v3));
        *(float4*)&Bs[ks][c4] = o;
        *(float4*)&xcT[(size_t)dch * RT + col0 + c4] = o;   // own channel range
        __syncthreads();
#pragma unroll
        for (int k = 0; k < 32; ++k) {
            float bv = Bs[k][col];
#pragma unroll
            for (int m = 0; m < 6; ++m)
                acc[m] = fmaf(ar[m][k0 + k], bv, acc[m]);
        }
        __syncthreads();
    }
#pragma unroll
    for (int m = 0; m < 6; ++m)
        if (mb + m < 44)
            atomicAdd(&xdT[(mb + m) * RT + col0 + col], acc[m]);
}

// ---------------------------------------------------------------------------
// K4a: per-segment scan from h=0; dt computed inline from dtr rows of xdT.
// Emits P = exp(a*sum(dt)) (== prod(dA)), Hf = final h.
// R12: grid.x = 15 — segment 15's summary is never consumed by part2.
// grid (15 seg, 24 dblk, 8 b), block 256.
__global__ __launch_bounds__(256) void scan_part1(const float* __restrict__ xdT,
                                                  const float* __restrict__ xcT,
                                                  const float* __restrict__ dtw,
                                                  const float* __restrict__ dtb,
                                                  const float* __restrict__ A_log,
                                                  float* __restrict__ P,
                                                  float* __restrict__ Hf) {
    __shared__ float dt_s[16][20], g_s[16][20], B_s[16][20];
    __shared__ float dtr_s[12][17];
    __shared__ float dtw_s[192];
    __shared__ float dtb_s[16];
    int seg = blockIdx.x, d0 = blockIdx.y * 16, b = blockIdx.z;
    int row0 = b * LL + seg * SEGL;
    int tid = threadIdx.x;
    int lane = tid & 63;
    int n = lane & 15;
    int dl = ((tid >> 6) << 2) | (lane >> 4);
    int tdd = tid >> 4, ti = tid & 15;
    if (tid < 192) dtw_s[tid] = dtw[d0 * DT_RANK + tid];
    if (tid < 16)  dtb_s[tid] = dtb[d0 + tid];
    float a = -__expf(A_log[(d0 + dl) * NS + n]);
    float h = 0.f, sdt = 0.f;
    for (int ch = 0; ch < 4; ++ch) {
        int r = row0 + ch * 16;
        float xv = xcT[(d0 + tdd) * RT + r + ti];
        B_s[tdd][ti] = xdT[(12 + tdd) * RT + r + ti];
        if (tid < 192) dtr_s[tid >> 4][ti] = xdT[(tid >> 4) * RT + r + ti];
        __syncthreads();     // staging ready (prev chunk's preloads done)
        float acc = dtb_s[tdd];
#pragma unroll
        for (int rr = 0; rr < DT_RANK; ++rr)
            acc = fmaf(dtr_s[rr][ti], dtw_s[tdd * DT_RANK + rr], acc);
        float dtv = fmaxf(acc, 0.f) + __logf(1.f + __expf(-fabsf(acc)));
        dt_s[tdd][ti] = dtv;
        g_s[tdd][ti]  = dtv * xv;
        __syncthreads();     // dt_s/g_s ready
        float dv[16], gb[16];
#pragma unroll
        for (int q = 0; q < 4; ++q) {
            float4 d4 = *(const float4*)&dt_s[dl][q * 4];   // broadcast within row
            float4 g4 = *(const float4*)&g_s[dl][q * 4];
            float4 b4 = *(const float4*)&B_s[n][q * 4];
            dv[q * 4 + 0] = d4.x; dv[q * 4 + 1] = d4.y;
            dv[q * 4 + 2] = d4.z; dv[q * 4 + 3] = d4.w;
            gb[q * 4 + 0] = g4.x * b4.x; gb[q * 4 + 1] = g4.y * b4.y;
            gb[q * 4 + 2] = g4.z * b4.z; gb[q * 4 + 3] = g4.w * b4.w;
        }
        __syncthreads();     // preload done -> next chunk may overwrite LDS
        float eh[16];
#pragma unroll
        for (int i = 0; i < 16; ++i) eh[i] = __expf(dv[i] * a);
#pragma unroll
        for (int i = 0; i < 16; ++i) {
            sdt += dv[i];
            h = fmaf(eh[i], h, gb[i]);
        }
    }
    int idx = ((seg * BB + b) * DI + d0 + dl) * NS + n;
    P[idx] = __expf(a * sdt);
    Hf[idx] = h;
}

// ---------------------------------------------------------------------------
// K4b: rescan each segment; h_init computed in-block by folding the earlier
// segments' (P,Hf) summaries. R12: the per-step row_sum16 butterfly (8 ops
// x 16 steps, 15/16 lanes discarded) is replaced by a DEFERRED select-
// butterfly: store w[i]=h*C per step, then one 4-stage reduction at chunk
// end using the SAME pairing tree (0x140/0x141/0x4E/0xB1) with per-bit
// keeps -> lane n ends with y[i=n], BITWISE-IDENTICAL association to the
// old code (absmax must not change). ~84 fewer VALU ops/chunk/thread.
__global__ __launch_bounds__(256) void scan_part2(const float* __restrict__ xdT,
                                                  const float* __restrict__ xcT,
                                                  const float* __restrict__ zsT,
                                                  const float* __restrict__ dtw,
                                                  const float* __restrict__ dtb,
                                                  const float* __restrict__ P,
                                                  const float* __restrict__ Hf,
                                                  const float* __restrict__ A_log,
                                                  const float* __restrict__ Dp,
                                                  float* __restrict__ yT) {
    __shared__ float dt_s[16][20], g_s[16][20], B_s[16][20], C_s[16][20];
    __shared__ float dtr_s[12][17];
    __shared__ float dtw_s[192];
    __shared__ float dtb_s[16];
    int seg = blockIdx.x, d0 = blockIdx.y * 16, b = blockIdx.z;
    int row0 = b * LL + seg * SEGL;
    int tid = threadIdx.x;
    int lane = tid & 63;
    int n = lane & 15;
    int dl = ((tid >> 6) << 2) | (lane >> 4);
    int d = d0 + dl;
    int tdd = tid >> 4, ti = tid & 15;
    if (tid < 192) dtw_s[tid] = dtw[d0 * DT_RANK + tid];
    if (tid < 16)  dtb_s[tid] = dtb[d0 + tid];
    float a = -__expf(A_log[d * NS + n]);
    float Dpd = Dp[d];
    bool b3 = (n & 8) != 0, b2 = (n & 4) != 0, b1 = (n & 2) != 0, b0 = (n & 1) != 0;
    // h_init: fold earlier segments' summaries (coalesced loads)
    float h = 0.f;
    for (int s = 0; s < seg; ++s) {
        int off = ((s * BB + b) * DI + d) * NS + n;
        h = fmaf(P[off], h, Hf[off]);
    }
    for (int ch = 0; ch < 4; ++ch) {
        int r = row0 + ch * 16;
        // epilogue operands for the (dl,n) writer role (L1/L2-resident)
        float xr = xcT[(size_t)d * RT + r + n];
        float zr = zsT[(size_t)d * RT + r + n];
        // staging role (tdd,ti)
        float xv = xcT[(d0 + tdd) * RT + r + ti];
        B_s[tdd][ti] = xdT[(12 + tdd) * RT + r + ti];
        C_s[tdd][ti] = xdT[(28 + tdd) * RT + r + ti];
        if (tid < 192) dtr_s[tid >> 4][ti] = xdT[(tid >> 4) * RT + r + ti];
        __syncthreads();     // staging ready
        float acc = dtb_s[tdd];
#pragma unroll
        for (int rr = 0; rr < DT_RANK; ++rr)
            acc = fmaf(dtr_s[rr][ti], dtw_s[tdd * DT_RANK + rr], acc);
        float dtv = fmaxf(acc, 0.f) + __logf(1.f + __expf(-fabsf(acc)));
        dt_s[tdd][ti] = dtv;
        g_s[tdd][ti]  = dtv * xv;
        __syncthreads();     // dt_s/g_s ready
        float dv[16], gb[16], cv[16];
#pragma unroll
        for (int q = 0; q < 4; ++q) {
            float4 d4 = *(const float4*)&dt_s[dl][q * 4];
            float4 g4 = *(const float4*)&g_s[dl][q * 4];
            float4 b4 = *(const float4*)&B_s[n][q * 4];
            float4 c4 = *(const float4*)&C_s[n][q * 4];
            dv[q * 4 + 0] = d4.x; dv[q * 4 + 1] = d4.y;
            dv[q * 4 + 2] = d4.z; dv[q * 4 + 3] = d4.w;
            gb[q * 4 + 0] = g4.x * b4.x; gb[q * 4 + 1] = g4.y * b4.y;
            gb[q * 4 + 2] = g4.z * b4.z; gb[q * 4 + 3] = g4.w * b4.w;
            cv[q * 4 + 0] = c4.x; cv[q * 4 + 1] = c4.y;
            cv[q * 4 + 2] = c4.z; cv[q * 4 + 3] = c4.w;
        }
        __syncthreads();     // preload done -> next chunk may overwrite LDS
        float eh[16];
#pragma unroll
        for (int i = 0; i < 16; ++i) eh[i] = __expf(dv[i] * a);
        // recurrence; w[i] = h_after_step_i * C[n][i]
        float w[16];
#pragma unroll
        for (int i = 0; i < 16; ++i) {
            h = fmaf(eh[i], h, gb[i]);
            w[i] = h * cv[i];
        }
        // deferred select-butterfly: lane n ends with y[i=n], same tree as
        // the old per-step row_sum16 (stages xor15, xor7, xor2, xor1).
        float A8[8];
#pragma unroll
        for (int jj = 0; jj < 8; ++jj) {
            float snd = b3 ? w[jj] : w[jj + 8];
            float rcv = DPPF(snd, 0x140);
            A8[jj] = (b3 ? w[jj + 8] : w[jj]) + rcv;
        }
        float A4[4];
#pragma unroll
        for (int jj = 0; jj < 4; ++jj) {
            float snd = b2 ? A8[jj] : A8[jj + 4];
            float rcv = DPPF(snd, 0x141);
            A4[jj] = (b2 ? A8[jj + 4] : A8[jj]) + rcv;
        }
        float A2[2];
#pragma unroll
        for (int jj = 0; jj < 2; ++jj) {
            float snd = b1 ? A2[0] : 0.f;  // placeholder (overwritten below)
            (void)snd;
            float s2 = b1 ? A4[jj] : A4[jj + 2];
            float rcv = DPPF(s2, 0x4E);
            A2[jj] = (b1 ? A4[jj + 2] : A4[jj]) + rcv;
        }
        float s1 = b0 ? A2[0] : A2[1];
        float rcv1 = DPPF(s1, 0xB1);
        float yacc = (b0 ? A2[1] : A2[0]) + rcv1;
        yT[(size_t)d * RT + r + n] = fmaf(xr, Dpd, yacc) * zr;
    }
}

// ---------------------------------------------------------------------------
// K5: out[b, c, l] = sum_d yT[d, row] * out_w[c, d]  via split-bf16 MFMA.
// (R8-proven.) grid (128, 3), 256 thr, 8KB LDS.
__global__ __launch_bounds__(256) void gemm_out(const float* __restrict__ yT,
                                                const unsigned short* __restrict__ owhi,
                                                const unsigned short* __restrict__ owlo,
                                                float* __restrict__ out) {
    __shared__ unsigned short yhi[2048];   // [kb][col][e] 4KB
    __shared__ unsigned short ylo[2048];
    int r0 = blockIdx.x * 64;
    int c0 = blockIdx.y * 64;
    int b  = r0 >> 10;
    int l0 = r0 & 1023;
    int tid = threadIdx.x;
    int lane = tid & 63;
    int wid = tid >> 6;          // wave id = staging kb
    int cw = c0 + wid * 16;
    const float* yb = yT + r0 + lane;      // staging col = lane
    f32x4 z4 = {0.f, 0.f, 0.f, 0.f};
    f32x4 acc[4] = {z4, z4, z4, z4};
    int arow = cw + (lane & 15);           // A fragment row (c)
    int akb  = (lane >> 4) * 8;            // A fragment k sub-block
    for (int ks = 0; ks < 12; ++ks) {
        int k0 = ks * 32;
        float v[8];
#pragma unroll
        for (int e = 0; e < 8; ++e) v[e] = yb[(size_t)(k0 + wid * 8 + e) * RT];
        union U8 { unsigned short u[8]; bf16x8 v8; } hv, lv;
#pragma unroll
        for (int e = 0; e < 8; ++e) {
            unsigned short h = f2bf(v[e]);
            hv.u[e] = h;
            lv.u[e] = f2bf(v[e] - bf2f(h));
        }
        *(bf16x8*)&yhi[(wid * 64 + lane) * 8] = hv.v8;
        *(bf16x8*)&ylo[(wid * 64 + lane) * 8] = lv.v8;
        __syncthreads();
        int aoff = arow * DI + k0 + akb;
        bf16x8 ah = *(const bf16x8*)&owhi[aoff];
        bf16x8 al = *(const bf16x8*)&owlo[aoff];
#pragma unroll
        for (int rt = 0; rt < 4; ++rt) {
            int boff = ((lane >> 4) * 64 + rt * 16 + (lane & 15)) * 8;
            bf16x8 bh = *(const bf16x8*)&yhi[boff];
            bf16x8 bl = *(const bf16x8*)&ylo[boff];
            acc[rt] = __builtin_amdgcn_mfma_f32_16x16x32_bf16(ah, bh, acc[rt], 0, 0, 0);
            acc[rt] = __builtin_amdgcn_mfma_f32_16x16x32_bf16(ah, bl, acc[rt], 0, 0, 0);
            acc[rt] = __builtin_amdgcn_mfma_f32_16x16x32_bf16(al, bh, acc[rt], 0, 0, 0);
        }
        __syncthreads();
    }
    float* ob = out + b * CC * LL;
#pragma unroll
    for (int rt = 0; rt < 4; ++rt) {
        int lbase = l0 + rt * 16 + (lane & 15);
#pragma unroll
        for (int reg = 0; reg < 4; ++reg) {
            int c = cw + (lane >> 4) * 4 + reg;
            ob[c * LL + lbase] = acc[rt][reg];
        }
    }
}

// ---------------------------------------------------------------------------
extern "C" void kernel_launch(void* const* d_in, const int* in_sizes, int n_in,
                              void* d_out, int out_size, void* d_ws, size_t ws_size,
                              hipStream_t stream) {
    const float* x         = (const float*)d_in[0];
    const float* proj_w    = (const float*)d_in[1];
    const float* proj_b    = (const float*)d_in[2];
    const float* in_proj_w = (const float*)d_in[3];
    const float* conv_w    = (const float*)d_in[4];
    const float* conv_b    = (const float*)d_in[5];
    const float* xproj_w   = (const float*)d_in[6];
    const float* dtproj_w  = (const float*)d_in[7];
    const float* dtproj_b  = (const float*)d_in[8];
    const float* A_log     = (const float*)d_in[9];
    const float* Dp        = (const float*)d_in[10];
    const float* out_w     = (const float*)d_in[11];
    float* out = (float*)d_out;

    float* ws    = (float*)d_ws;
    unsigned short* W2hi = (unsigned short*)ws;          // 147456 bf16 = 73728 f32 slots
    unsigned short* W2lo = (unsigned short*)(ws + 73728);
    float* bias2 = ws + 147456;           // 768
    float* xzT   = bias2 + 768;           // 768*8192 = 6291456 (x raw, z silu'd)
    float* xcT   = xzT + 6291456;         // 3145728
    float* yT    = xcT + 3145728;         // 3145728
    float* xdT   = yT + 3145728;          // 44*8192 = 360448 (0-11 dtr, 12-27 B, 28-43 C)
    float* P     = xdT + 360448;          // 786432
    float* Hf    = P + 786432;            // 786432
    unsigned short* owhi = (unsigned short*)(Hf + 786432);       // 73728 bf16
    unsigned short* owlo = (unsigned short*)(Hf + 786432 + 36864);
    float* zsT   = xzT + DI * RT;         // z half, silu applied by gemm_xz epilogue

    fuse_w_kernel<<<768, 192, 0, stream>>>(in_proj_w, proj_w, proj_b, out_w,
                                           W2hi, W2lo, owhi, owlo, bias2, xdT);
    gemm_xz<<<dim3(128, 6), 256, 0, stream>>>(x, W2hi, W2lo, bias2, xzT);
    xproj_conv_gemm<<<dim3(128, 4), 512, 0, stream>>>(xzT, conv_w, conv_b,
                                                      xproj_w, xcT, xdT);
    scan_part1<<<dim3(15, 24, 8), 256, 0, stream>>>(xdT, xcT, dtproj_w, dtproj_b,
                                                    A_log, P, Hf);
    scan_part2<<<dim3(16, 24, 8), 256, 0, stream>>>(xdT, xcT, zsT, dtproj_w, dtproj_b,
                                                    P, Hf, A_log, Dp, yT);
    gemm_out<<<dim3(128, 3), 256, 0, stream>>>(yT, owhi, owlo, out);
}

// Round 13
// 192.308 us; speedup vs baseline: 1.3414x; 1.0254x over previous
//
#include <hip/hip_runtime.h>
#include <math.h>

// Problem constants (B=8, C=192, H=W=32)
#define BB 8
#define CC 192
#define LL 1024
#define RT 8192         // total rows = BB*LL
#define DI 384          // d_inner
#define DT_RANK 12
#define NS 16           // D_STATE
#define NSEG 16
#define SEGL 64

typedef __attribute__((ext_vector_type(8))) short bf16x8;   // 8 bf16 (4 VGPRs)
typedef __attribute__((ext_vector_type(4))) float f32x4;

// RNE float->bf16 and back, manual (no header dependency)
__device__ __forceinline__ unsigned short f2bf(float f) {
    unsigned u = __float_as_uint(f);
    unsigned r = (u + 0x7FFFu + ((u >> 16) & 1u)) >> 16;
    return (unsigned short)r;
}
__device__ __forceinline__ float bf2f(unsigned short h) {
    return __uint_as_float(((unsigned)h) << 16);
}

// row-level DPP shuffle (16-lane rows), compile-time ctrl
#define DPPF(v, ctrl) __int_as_float(__builtin_amdgcn_update_dpp(0, __float_as_int(v), ctrl, 0xF, 0xF, true))

// ---------------------------------------------------------------------------
// K1: W2[j,c'] = sum_c in_proj_w[j,c]*proj_w[c,c'], emitted as SPLIT bf16
// planes W2hi/W2lo (w = hi + lo) for the MFMA gemm_xz. Also splits out_w
// into owhi/owlo planes. bias2[j] = in_proj_w[j,:]·proj_b. Zero-inits xdT.
__global__ void fuse_w_kernel(const float* __restrict__ in_proj_w,
                              const float* __restrict__ proj_w,
                              const float* __restrict__ proj_b,
                              const float* __restrict__ out_w,
                              unsigned short* __restrict__ W2hi,
                              unsigned short* __restrict__ W2lo,
                              unsigned short* __restrict__ owhi,
                              unsigned short* __restrict__ owlo,
                              float* __restrict__ bias2,
                              float* __restrict__ xdT) {
    int j = blockIdx.x;
    int cp = threadIdx.x;
    int gtid = j * CC + cp;                       // 0..147455
    for (int i = gtid; i < 44 * RT; i += 768 * CC) xdT[i] = 0.f;
    if (j < DI) {
        float v = out_w[cp * DI + j];
        unsigned short h = f2bf(v);
        owhi[cp * DI + j] = h;
        owlo[cp * DI + j] = f2bf(v - bf2f(h));
    }
    __shared__ float wrow[CC];
    wrow[cp] = in_proj_w[j * CC + cp];
    __syncthreads();
    float acc = 0.f;
#pragma unroll 4
    for (int c = 0; c < CC; ++c) acc = fmaf(wrow[c], proj_w[c * CC + cp], acc);
    unsigned short h = f2bf(acc);
    W2hi[j * CC + cp] = h;
    W2lo[j * CC + cp] = f2bf(acc - bf2f(h));
    if (cp == 0) {
        float b = 0.f;
        for (int c = 0; c < CC; ++c) b = fmaf(wrow[c], proj_b[c], b);
        bias2[j] = b;
    }
}

// ---------------------------------------------------------------------------
// K2: xzT[j, row] = sum_c x[b,c,l]*W2[j,c] + bias2[j]  via split-bf16 MFMA.
// D = Whi*Xhi + Whi*Xlo + Wlo*Xhi (3x mfma_f32_16x16x32_bf16), ~2^-18 rel.
// j-tile 128 (R12-proven). grid (128,6), 256 thr, 8KB LDS.
__global__ __launch_bounds__(256) void gemm_xz(const float* __restrict__ x,
                                               const unsigned short* __restrict__ W2hi,
                                               const unsigned short* __restrict__ W2lo,
                                               const float* __restrict__ bias2,
                                               float* __restrict__ xzT) {
    __shared__ unsigned short xhi[2048];   // [kb][col][e] 4KB
    __shared__ unsigned short xlo[2048];
    int r0 = blockIdx.x * 64;
    int j0 = blockIdx.y * 128;
    int b  = r0 >> 10;
    int l0 = r0 & 1023;
    int tid = threadIdx.x;
    int lane = tid & 63;
    int wid = tid >> 6;          // wave id = staging kb
    int jw = j0 + wid * 16;      // sub-tile 0; sub-tile 1 at +64
    const float* xb = x + b * CC * LL + l0 + lane;   // staging col = lane
    f32x4 z4 = {0.f, 0.f, 0.f, 0.f};
    f32x4 acc[2][4] = {{z4, z4, z4, z4}, {z4, z4, z4, z4}};
    int arow = lane & 15;                  // A fragment row offset (j)
    int akb  = (lane >> 4) * 8;            // A fragment k sub-block
    for (int ks = 0; ks < 6; ++ks) {
        int k0 = ks * 32;
        float v[8];
#pragma unroll
        for (int e = 0; e < 8; ++e) v[e] = xb[(k0 + wid * 8 + e) * LL];
        union U8 { unsigned short u[8]; bf16x8 v8; } hv, lv;
#pragma unroll
        for (int e = 0; e < 8; ++e) {
            unsigned short h = f2bf(v[e]);
            hv.u[e] = h;
            lv.u[e] = f2bf(v[e] - bf2f(h));
        }
        *(bf16x8*)&xhi[(wid * 64 + lane) * 8] = hv.v8;
        *(bf16x8*)&xlo[(wid * 64 + lane) * 8] = lv.v8;
        __syncthreads();
        int aoff0 = (jw + arow) * CC + k0 + akb;
        int aoff1 = aoff0 + 64 * CC;
        bf16x8 ah0 = *(const bf16x8*)&W2hi[aoff0];
        bf16x8 al0 = *(const bf16x8*)&W2lo[aoff0];
        bf16x8 ah1 = *(const bf16x8*)&W2hi[aoff1];
        bf16x8 al1 = *(const bf16x8*)&W2lo[aoff1];
#pragma unroll
        for (int rt = 0; rt < 4; ++rt) {
            int boff = ((lane >> 4) * 64 + rt * 16 + (lane & 15)) * 8;
            bf16x8 bh = *(const bf16x8*)&xhi[boff];
            bf16x8 bl = *(const bf16x8*)&xlo[boff];
            acc[0][rt] = __builtin_amdgcn_mfma_f32_16x16x32_bf16(ah0, bh, acc[0][rt], 0, 0, 0);
            acc[0][rt] = __builtin_amdgcn_mfma_f32_16x16x32_bf16(ah0, bl, acc[0][rt], 0, 0, 0);
            acc[0][rt] = __builtin_amdgcn_mfma_f32_16x16x32_bf16(al0, bh, acc[0][rt], 0, 0, 0);
            acc[1][rt] = __builtin_amdgcn_mfma_f32_16x16x32_bf16(ah1, bh, acc[1][rt], 0, 0, 0);
            acc[1][rt] = __builtin_amdgcn_mfma_f32_16x16x32_bf16(ah1, bl, acc[1][rt], 0, 0, 0);
            acc[1][rt] = __builtin_amdgcn_mfma_f32_16x16x32_bf16(al1, bh, acc[1][rt], 0, 0, 0);
        }
        __syncthreads();
    }
    bool is_z = (j0 >= DI);   // j0 in {0,128,256,384,512,640}; DI=384=3*128
#pragma unroll
    for (int js = 0; js < 2; ++js) {
#pragma unroll
        for (int rt = 0; rt < 4; ++rt) {
            int rbase = r0 + rt * 16 + (lane & 15);
#pragma unroll
            for (int reg = 0; reg < 4; ++reg) {
                int j = jw + js * 64 + (lane >> 4) * 4 + reg;
                float o = acc[js][rt][reg] + bias2[j];
                if (is_z) o = __fdividef(o, 1.f + __expf(-o));
                xzT[j * RT + rbase] = o;
            }
        }
    }
}

// ---------------------------------------------------------------------------
// K3: skinny GEMM with fused causal depthwise conv (k=4) + silu in staging.
// 4-way K-split (R11-proven). grid (128,4), 512 thr.
__global__ __launch_bounds__(512) void xproj_conv_gemm(const float* __restrict__ xzT,
                                                       const float* __restrict__ conv_w,
                                                       const float* __restrict__ conv_b,
                                                       const float* __restrict__ aw,
                                                       float* __restrict__ xcT,
                                                       float* __restrict__ xdT) {
    __shared__ float Bs[32][64];
    int col0 = blockIdx.x * 64;
    int kbase = blockIdx.y * 96;
    int tid = threadIdx.x;
    int col = tid & 63, mg = tid >> 6;          // mg wave-uniform -> scalar A loads
    int mb = mg * 6;                             // rows mb..mb+5 (44..47 discarded)
    const float* ar[6];
#pragma unroll
    for (int m = 0; m < 6; ++m) ar[m] = aw + min(mb + m, 43) * DI + kbase;
    float acc[6] = {};
    int ks = tid >> 4, c4 = (tid & 15) * 4;
    bool atL0 = ((col0 & 1023) == 0) && (c4 == 0);   // conv zero-pad boundary
    for (int k0 = 0; k0 < 96; k0 += 32) {
        int dch = kbase + k0 + ks;
        const float* src = xzT + (size_t)dch * RT + col0 + c4;
        float4 cur = *(const float4*)src;
        float4 prev = make_float4(0.f, 0.f, 0.f, 0.f);
        if (!atL0) prev = *(const float4*)(src - 4);
        float4 w4 = *(const float4*)&conv_w[dch * 4];   // w0=x w1=y w2=z w3=w
        float bb = conv_b[dch];
        float v0 = bb + w4.w * cur.x + w4.z * prev.w + w4.y * prev.z + w4.x * prev.y;
        float v1 = bb + w4.w * cur.y + w4.z * cur.x  + w4.y * prev.w + w4.x * prev.z;
        float v2 = bb + w4.w * cur.z + w4.z * cur.y  + w4.y * cur.x  + w4.x * prev.w;
        float v3 = bb + w4.w * cur.w + w4.z * cur.z  + w4.y * cur.y  + w4.x * cur.x;
        float4 o;
        o.x = __fdividef(v0, 1.f + __expf(-v0));
        o.y = __fdividef(v1, 1.f + __expf(-v1));
        o.z = __fdividef(v2, 1.f + __expf(-v2));
        o.w = __fdividef(v3, 1.f + __expf(-v3));
        *(float4*)&Bs[ks][c4] = o;
        *(float4*)&xcT[(size_t)dch * RT + col0 + c4] = o;   // own channel range
        __syncthreads();
#pragma unroll
        for (int k = 0; k < 32; ++k) {
            float bv = Bs[k][col];
#pragma unroll
            for (int m = 0; m < 6; ++m)
                acc[m] = fmaf(ar[m][k0 + k], bv, acc[m]);
        }
        __syncthreads();
    }
#pragma unroll
    for (int m = 0; m < 6; ++m)
        if (mb + m < 44)
            atomicAdd(&xdT[(mb + m) * RT + col0 + col], acc[m]);
}

// ---------------------------------------------------------------------------
// K4a (R13): per-segment scan from h=0. WHOLE 64-step segment staged ONCE
// (float4-wide loads, 4x fewer), one dt-compute phase (each thread does 4
// cols, same per-col fmaf order -> bitwise-identical), recurrence reads LDS
// with NO further barriers. Barriers/block: 12 -> 2. 16.6KB LDS.
// grid (15 seg, 24 dblk, 8 b), block 256.
__global__ __launch_bounds__(256) void scan_part1(const float* __restrict__ xdT,
                                                  const float* __restrict__ xcT,
                                                  const float* __restrict__ dtw,
                                                  const float* __restrict__ dtb,
                                                  const float* __restrict__ A_log,
                                                  float* __restrict__ P,
                                                  float* __restrict__ Hf) {
    __shared__ float dt_s[16][68], g_s[16][68], B_s[16][68];
    __shared__ float dtr_s[12][68];
    __shared__ float dtw_s[192];
    __shared__ float dtb_s[16];
    int seg = blockIdx.x, d0 = blockIdx.y * 16, b = blockIdx.z;
    int row0 = b * LL + seg * SEGL;
    int tid = threadIdx.x;
    int lane = tid & 63;
    int n = lane & 15;
    int dl = ((tid >> 6) << 2) | (lane >> 4);
    int tdd = tid >> 4, ti = tid & 15;
    if (tid < 192) dtw_s[tid] = dtw[d0 * DT_RANK + tid];
    if (tid < 16)  dtb_s[tid] = dtb[d0 + tid];
    float a = -__expf(A_log[(d0 + dl) * NS + n]);
    // ---- stage entire segment (float4-wide)
    *(float4*)&B_s[tdd][ti * 4] = *(const float4*)&xdT[(12 + tdd) * RT + row0 + ti * 4];
    if (tid < 192)
        *(float4*)&dtr_s[tid >> 4][ti * 4] = *(const float4*)&xdT[(tid >> 4) * RT + row0 + ti * 4];
    float4 xv4 = *(const float4*)&xcT[(d0 + tdd) * RT + row0 + ti * 4];
    float xv[4] = {xv4.x, xv4.y, xv4.z, xv4.w};
    __syncthreads();
    // ---- dt compute: 4 cols per thread (same per-col fmaf order as before)
#pragma unroll
    for (int q = 0; q < 4; ++q) {
        int col = ti * 4 + q;
        float acc = dtb_s[tdd];
#pragma unroll
        for (int rr = 0; rr < DT_RANK; ++rr)
            acc = fmaf(dtr_s[rr][col], dtw_s[tdd * DT_RANK + rr], acc);
        float dtv = fmaxf(acc, 0.f) + __logf(1.f + __expf(-fabsf(acc)));
        dt_s[tdd][col] = dtv;
        g_s[tdd][col]  = dtv * xv[q];
    }
    __syncthreads();
    // ---- recurrence, barrier-free
    float h = 0.f, sdt = 0.f;
    for (int ch = 0; ch < 4; ++ch) {
        int c0 = ch * 16;
        float dv[16], gb[16];
#pragma unroll
        for (int q = 0; q < 4; ++q) {
            float4 d4 = *(const float4*)&dt_s[dl][c0 + q * 4];   // row-broadcast
            float4 g4 = *(const float4*)&g_s[dl][c0 + q * 4];
            float4 b4 = *(const float4*)&B_s[n][c0 + q * 4];
            dv[q * 4 + 0] = d4.x; dv[q * 4 + 1] = d4.y;
            dv[q * 4 + 2] = d4.z; dv[q * 4 + 3] = d4.w;
            gb[q * 4 + 0] = g4.x * b4.x; gb[q * 4 + 1] = g4.y * b4.y;
            gb[q * 4 + 2] = g4.z * b4.z; gb[q * 4 + 3] = g4.w * b4.w;
        }
        float eh[16];
#pragma unroll
        for (int i = 0; i < 16; ++i) eh[i] = __expf(dv[i] * a);
#pragma unroll
        for (int i = 0; i < 16; ++i) {
            sdt += dv[i];
            h = fmaf(eh[i], h, gb[i]);
        }
    }
    int idx = ((seg * BB + b) * DI + d0 + dl) * NS + n;
    P[idx] = __expf(a * sdt);
    Hf[idx] = h;
}

// ---------------------------------------------------------------------------
// K4b (R13): rescan each segment from folded h_init. Whole-segment staging
// as in part1 (barriers 12 -> 2); deferred select-butterfly per 16-step
// sub-chunk (R12-proven, bitwise-identical). 21.0KB LDS.
// grid (16 seg, 24 dblk, 8 b), block 256.
__global__ __launch_bounds__(256) void scan_part2(const float* __restrict__ xdT,
                                                  const float* __restrict__ xcT,
                                                  const float* __restrict__ zsT,
                                                  const float* __restrict__ dtw,
                                                  const float* __restrict__ dtb,
                                                  const float* __restrict__ P,
                                                  const float* __restrict__ Hf,
                                                  const float* __restrict__ A_log,
                                                  const float* __restrict__ Dp,
                                                  float* __restrict__ yT) {
    __shared__ float dt_s[16][68], g_s[16][68], B_s[16][68], C_s[16][68];
    __shared__ float dtr_s[12][68];
    __shared__ float dtw_s[192];
    __shared__ float dtb_s[16];
    int seg = blockIdx.x, d0 = blockIdx.y * 16, b = blockIdx.z;
    int row0 = b * LL + seg * SEGL;
    int tid = threadIdx.x;
    int lane = tid & 63;
    int n = lane & 15;
    int dl = ((tid >> 6) << 2) | (lane >> 4);
    int d = d0 + dl;
    int tdd = tid >> 4, ti = tid & 15;
    if (tid < 192) dtw_s[tid] = dtw[d0 * DT_RANK + tid];
    if (tid < 16)  dtb_s[tid] = dtb[d0 + tid];
    float a = -__expf(A_log[d * NS + n]);
    float Dpd = Dp[d];
    bool b3 = (n & 8) != 0, b2 = (n & 4) != 0, b1 = (n & 2) != 0, b0 = (n & 1) != 0;
    // ---- stage entire segment (float4-wide)
    *(float4*)&B_s[tdd][ti * 4] = *(const float4*)&xdT[(12 + tdd) * RT + row0 + ti * 4];
    *(float4*)&C_s[tdd][ti * 4] = *(const float4*)&xdT[(28 + tdd) * RT + row0 + ti * 4];
    if (tid < 192)
        *(float4*)&dtr_s[tid >> 4][ti * 4] = *(const float4*)&xdT[(tid >> 4) * RT + row0 + ti * 4];
    float4 xv4 = *(const float4*)&xcT[(d0 + tdd) * RT + row0 + ti * 4];
    float xv[4] = {xv4.x, xv4.y, xv4.z, xv4.w};
    // h_init: fold earlier segments' summaries (coalesced loads)
    float h = 0.f;
    for (int s = 0; s < seg; ++s) {
        int off = ((s * BB + b) * DI + d) * NS + n;
        h = fmaf(P[off], h, Hf[off]);
    }
    __syncthreads();
    // ---- dt compute: 4 cols per thread
#pragma unroll
    for (int q = 0; q < 4; ++q) {
        int col = ti * 4 + q;
        float acc = dtb_s[tdd];
#pragma unroll
        for (int rr = 0; rr < DT_RANK; ++rr)
            acc = fmaf(dtr_s[rr][col], dtw_s[tdd * DT_RANK + rr], acc);
        float dtv = fmaxf(acc, 0.f) + __logf(1.f + __expf(-fabsf(acc)));
        dt_s[tdd][col] = dtv;
        g_s[tdd][col]  = dtv * xv[q];
    }
    __syncthreads();
    // ---- recurrence over 4 sub-chunks, barrier-free
    for (int ch = 0; ch < 4; ++ch) {
        int c0 = ch * 16;
        int r = row0 + c0;
        float xr = xcT[(size_t)d * RT + r + n];
        float zr = zsT[(size_t)d * RT + r + n];
        float dv[16], gb[16], cv[16];
#pragma unroll
        for (int q = 0; q < 4; ++q) {
            float4 d4 = *(const float4*)&dt_s[dl][c0 + q * 4];
            float4 g4 = *(const float4*)&g_s[dl][c0 + q * 4];
            float4 b4 = *(const float4*)&B_s[n][c0 + q * 4];
            float4 c4 = *(const float4*)&C_s[n][c0 + q * 4];
            dv[q * 4 + 0] = d4.x; dv[q * 4 + 1] = d4.y;
            dv[q * 4 + 2] = d4.z; dv[q * 4 + 3] = d4.w;
            gb[q * 4 + 0] = g4.x * b4.x; gb[q * 4 + 1] = g4.y * b4.y;
            gb[q * 4 + 2] = g4.z * b4.z; gb[q * 4 + 3] = g4.w * b4.w;
            cv[q * 4 + 0] = c4.x; cv[q * 4 + 1] = c4.y;
            cv[q * 4 + 2] = c4.z; cv[q * 4 + 3] = c4.w;
        }
        float eh[16];
#pragma unroll
        for (int i = 0; i < 16; ++i) eh[i] = __expf(dv[i] * a);
        // recurrence; w[i] = h_after_step_i * C[n][i]
        float w[16];
#pragma unroll
        for (int i = 0; i < 16; ++i) {
            h = fmaf(eh[i], h, gb[i]);
            w[i] = h * cv[i];
        }
        // deferred select-butterfly (R12-proven, bitwise-identical tree)
        float A8[8];
#pragma unroll
        for (int jj = 0; jj < 8; ++jj) {
            float snd = b3 ? w[jj] : w[jj + 8];
            float rcv = DPPF(snd, 0x140);
            A8[jj] = (b3 ? w[jj + 8] : w[jj]) + rcv;
        }
        float A4[4];
#pragma unroll
        for (int jj = 0; jj < 4; ++jj) {
            float snd = b2 ? A8[jj] : A8[jj + 4];
            float rcv = DPPF(snd, 0x141);
            A4[jj] = (b2 ? A8[jj + 4] : A8[jj]) + rcv;
        }
        float A2[2];
#pragma unroll
        for (int jj = 0; jj < 2; ++jj) {
            float s2 = b1 ? A4[jj] : A4[jj + 2];
            float rcv = DPPF(s2, 0x4E);
            A2[jj] = (b1 ? A4[jj + 2] : A4[jj]) + rcv;
        }
        float s1 = b0 ? A2[0] : A2[1];
        float rcv1 = DPPF(s1, 0xB1);
        float yacc = (b0 ? A2[1] : A2[0]) + rcv1;
        yT[(size_t)d * RT + r + n] = fmaf(xr, Dpd, yacc) * zr;
    }
}

// ---------------------------------------------------------------------------
// K5: out[b, c, l] = sum_d yT[d, row] * out_w[c, d]  via split-bf16 MFMA.
// (R8-proven.) grid (128, 3), 256 thr, 8KB LDS.
__global__ __launch_bounds__(256) void gemm_out(const float* __restrict__ yT,
                                                const unsigned short* __restrict__ owhi,
                                                const unsigned short* __restrict__ owlo,
                                                float* __restrict__ out) {
    __shared__ unsigned short yhi[2048];   // [kb][col][e] 4KB
    __shared__ unsigned short ylo[2048];
    int r0 = blockIdx.x * 64;
    int c0 = blockIdx.y * 64;
    int b  = r0 >> 10;
    int l0 = r0 & 1023;
    int tid = threadIdx.x;
    int lane = tid & 63;
    int wid = tid >> 6;          // wave id = staging kb
    int cw = c0 + wid * 16;
    const float* yb = yT + r0 + lane;      // staging col = lane
    f32x4 z4 = {0.f, 0.f, 0.f, 0.f};
    f32x4 acc[4] = {z4, z4, z4, z4};
    int arow = cw + (lane & 15);           // A fragment row (c)
    int akb  = (lane >> 4) * 8;            // A fragment k sub-block
    for (int ks = 0; ks < 12; ++ks) {
        int k0 = ks * 32;
        float v[8];
#pragma unroll
        for (int e = 0; e < 8; ++e) v[e] = yb[(size_t)(k0 + wid * 8 + e) * RT];
        union U8 { unsigned short u[8]; bf16x8 v8; } hv, lv;
#pragma unroll
        for (int e = 0; e < 8; ++e) {
            unsigned short h = f2bf(v[e]);
            hv.u[e] = h;
            lv.u[e] = f2bf(v[e] - bf2f(h));
        }
        *(bf16x8*)&yhi[(wid * 64 + lane) * 8] = hv.v8;
        *(bf16x8*)&ylo[(wid * 64 + lane) * 8] = lv.v8;
        __syncthreads();
        int aoff = arow * DI + k0 + akb;
        bf16x8 ah = *(const bf16x8*)&owhi[aoff];
        bf16x8 al = *(const bf16x8*)&owlo[aoff];
#pragma unroll
        for (int rt = 0; rt < 4; ++rt) {
            int boff = ((lane >> 4) * 64 + rt * 16 + (lane & 15)) * 8;
            bf16x8 bh = *(const bf16x8*)&yhi[boff];
            bf16x8 bl = *(const bf16x8*)&ylo[boff];
            acc[rt] = __builtin_amdgcn_mfma_f32_16x16x32_bf16(ah, bh, acc[rt], 0, 0, 0);
            acc[rt] = __builtin_amdgcn_mfma_f32_16x16x32_bf16(ah, bl, acc[rt], 0, 0, 0);
            acc[rt] = __builtin_amdgcn_mfma_f32_16x16x32_bf16(al, bh, acc[rt], 0, 0, 0);
        }
        __syncthreads();
    }
    float* ob = out + b * CC * LL;
#pragma unroll
    for (int rt = 0; rt < 4; ++rt) {
        int lbase = l0 + rt * 16 + (lane & 15);
#pragma unroll
        for (int reg = 0; reg < 4; ++reg) {
            int c = cw + (lane >> 4) * 4 + reg;
            ob[c * LL + lbase] = acc[rt][reg];
        }
    }
}

// ---------------------------------------------------------------------------
extern "C" void kernel_launch(void* const* d_in, const int* in_sizes, int n_in,
                              void* d_out, int out_size, void* d_ws, size_t ws_size,
                              hipStream_t stream) {
    const float* x         = (const float*)d_in[0];
    const float* proj_w    = (const float*)d_in[1];
    const float* proj_b    = (const float*)d_in[2];
    const float* in_proj_w = (const float*)d_in[3];
    const float* conv_w    = (const float*)d_in[4];
    const float* conv_b    = (const float*)d_in[5];
    const float* xproj_w   = (const float*)d_in[6];
    const float* dtproj_w  = (const float*)d_in[7];
    const float* dtproj_b  = (const float*)d_in[8];
    const float* A_log     = (const float*)d_in[9];
    const float* Dp        = (const float*)d_in[10];
    const float* out_w     = (const float*)d_in[11];
    float* out = (float*)d_out;

    float* ws    = (float*)d_ws;
    unsigned short* W2hi = (unsigned short*)ws;          // 147456 bf16 = 73728 f32 slots
    unsigned short* W2lo = (unsigned short*)(ws + 73728);
    float* bias2 = ws + 147456;           // 768
    float* xzT   = bias2 + 768;           // 768*8192 = 6291456 (x raw, z silu'd)
    float* xcT   = xzT + 6291456;         // 3145728
    float* yT    = xcT + 3145728;         // 3145728
    float* xdT   = yT + 3145728;          // 44*8192 = 360448 (0-11 dtr, 12-27 B, 28-43 C)
    float* P     = xdT + 360448;          // 786432
    float* Hf    = P + 786432;            // 786432
    unsigned short* owhi = (unsigned short*)(Hf + 786432);       // 73728 bf16
    unsigned short* owlo = (unsigned short*)(Hf + 786432 + 36864);
    float* zsT   = xzT + DI * RT;         // z half, silu applied by gemm_xz epilogue

    fuse_w_kernel<<<768, 192, 0, stream>>>(in_proj_w, proj_w, proj_b, out_w,
                                           W2hi, W2lo, owhi, owlo, bias2, xdT);
    gemm_xz<<<dim3(128, 6), 256, 0, stream>>>(x, W2hi, W2lo, bias2, xzT);
    xproj_conv_gemm<<<dim3(128, 4), 512, 0, stream>>>(xzT, conv_w, conv_b,
                                                      xproj_w, xcT, xdT);
    scan_part1<<<dim3(15, 24, 8), 256, 0, stream>>>(xdT, xcT, dtproj_w, dtproj_b,
                                                    A_log, P, Hf);
    scan_part2<<<dim3(16, 24, 8), 256, 0, stream>>>(xdT, xcT, zsT, dtproj_w, dtproj_b,
                                                    P, Hf, A_log, Dp, yT);
    gemm_out<<<dim3(128, 3), 256, 0, stream>>>(yT, owhi, owlo, out);
}

// Round 14
// 182.880 us; speedup vs baseline: 1.4105x; 1.0516x over previous
//
#include <hip/hip_runtime.h>
#include <math.h>

// Problem constants (B=8, C=192, H=W=32)
#define BB 8
#define CC 192
#define LL 1024
#define RT 8192         // total rows = BB*LL
#define DI 384          // d_inner
#define DT_RANK 12
#define NS 16           // D_STATE
#define NSEG 16
#define SEGL 64

typedef __attribute__((ext_vector_type(8))) short bf16x8;   // 8 bf16 (4 VGPRs)
typedef __attribute__((ext_vector_type(4))) float f32x4;

// RNE float->bf16 and back, manual (no header dependency)
__device__ __forceinline__ unsigned short f2bf(float f) {
    unsigned u = __float_as_uint(f);
    unsigned r = (u + 0x7FFFu + ((u >> 16) & 1u)) >> 16;
    return (unsigned short)r;
}
__device__ __forceinline__ float bf2f(unsigned short h) {
    return __uint_as_float(((unsigned)h) << 16);
}

// row-level DPP shuffle (16-lane rows), compile-time ctrl
#define DPPF(v, ctrl) __int_as_float(__builtin_amdgcn_update_dpp(0, __float_as_int(v), ctrl, 0xF, 0xF, true))

// ---------------------------------------------------------------------------
// K1: W2[j,c'] = sum_c in_proj_w[j,c]*proj_w[c,c'], emitted as SPLIT bf16
// planes W2hi/W2lo (w = hi + lo) for the MFMA gemm_xz. Also splits out_w
// into owhi/owlo planes. bias2[j] = in_proj_w[j,:]·proj_b. Zero-inits xdT.
// R14: wrow read as float4 (48 ds_read_b128 vs 192 b32; c order preserved
// -> bitwise-identical).
__global__ void fuse_w_kernel(const float* __restrict__ in_proj_w,
                              const float* __restrict__ proj_w,
                              const float* __restrict__ proj_b,
                              const float* __restrict__ out_w,
                              unsigned short* __restrict__ W2hi,
                              unsigned short* __restrict__ W2lo,
                              unsigned short* __restrict__ owhi,
                              unsigned short* __restrict__ owlo,
                              float* __restrict__ bias2,
                              float* __restrict__ xdT) {
    int j = blockIdx.x;
    int cp = threadIdx.x;
    int gtid = j * CC + cp;                       // 0..147455
    for (int i = gtid; i < 44 * RT; i += 768 * CC) xdT[i] = 0.f;
    if (j < DI) {
        float v = out_w[cp * DI + j];
        unsigned short h = f2bf(v);
        owhi[cp * DI + j] = h;
        owlo[cp * DI + j] = f2bf(v - bf2f(h));
    }
    __shared__ float wrow[CC];
    wrow[cp] = in_proj_w[j * CC + cp];
    __syncthreads();
    float acc = 0.f;
    const float4* wrow4 = (const float4*)wrow;
#pragma unroll 4
    for (int c4 = 0; c4 < CC; c4 += 4) {
        float4 w4 = wrow4[c4 >> 2];
        acc = fmaf(w4.x, proj_w[(c4 + 0) * CC + cp], acc);
        acc = fmaf(w4.y, proj_w[(c4 + 1) * CC + cp], acc);
        acc = fmaf(w4.z, proj_w[(c4 + 2) * CC + cp], acc);
        acc = fmaf(w4.w, proj_w[(c4 + 3) * CC + cp], acc);
    }
    unsigned short h = f2bf(acc);
    W2hi[j * CC + cp] = h;
    W2lo[j * CC + cp] = f2bf(acc - bf2f(h));
    if (cp == 0) {
        float b = 0.f;
        for (int c = 0; c < CC; ++c) b = fmaf(wrow[c], proj_b[c], b);
        bias2[j] = b;
    }
}

// ---------------------------------------------------------------------------
// K2: xzT[j, row] = sum_c x[b,c,l]*W2[j,c] + bias2[j]  via split-bf16 MFMA.
// D = Whi*Xhi + Whi*Xlo + Wlo*Xhi (3x mfma_f32_16x16x32_bf16), ~2^-18 rel.
// j-tile 128 (R12-proven). grid (128,6), 256 thr, 8KB LDS.
__global__ __launch_bounds__(256) void gemm_xz(const float* __restrict__ x,
                                               const unsigned short* __restrict__ W2hi,
                                               const unsigned short* __restrict__ W2lo,
                                               const float* __restrict__ bias2,
                                               float* __restrict__ xzT) {
    __shared__ unsigned short xhi[2048];   // [kb][col][e] 4KB
    __shared__ unsigned short xlo[2048];
    int r0 = blockIdx.x * 64;
    int j0 = blockIdx.y * 128;
    int b  = r0 >> 10;
    int l0 = r0 & 1023;
    int tid = threadIdx.x;
    int lane = tid & 63;
    int wid = tid >> 6;          // wave id = staging kb
    int jw = j0 + wid * 16;      // sub-tile 0; sub-tile 1 at +64
    const float* xb = x + b * CC * LL + l0 + lane;   // staging col = lane
    f32x4 z4 = {0.f, 0.f, 0.f, 0.f};
    f32x4 acc[2][4] = {{z4, z4, z4, z4}, {z4, z4, z4, z4}};
    int arow = lane & 15;                  // A fragment row offset (j)
    int akb  = (lane >> 4) * 8;            // A fragment k sub-block
    for (int ks = 0; ks < 6; ++ks) {
        int k0 = ks * 32;
        float v[8];
#pragma unroll
        for (int e = 0; e < 8; ++e) v[e] = xb[(k0 + wid * 8 + e) * LL];
        union U8 { unsigned short u[8]; bf16x8 v8; } hv, lv;
#pragma unroll
        for (int e = 0; e < 8; ++e) {
            unsigned short h = f2bf(v[e]);
            hv.u[e] = h;
            lv.u[e] = f2bf(v[e] - bf2f(h));
        }
        *(bf16x8*)&xhi[(wid * 64 + lane) * 8] = hv.v8;
        *(bf16x8*)&xlo[(wid * 64 + lane) * 8] = lv.v8;
        __syncthreads();
        int aoff0 = (jw + arow) * CC + k0 + akb;
        int aoff1 = aoff0 + 64 * CC;
        bf16x8 ah0 = *(const bf16x8*)&W2hi[aoff0];
        bf16x8 al0 = *(const bf16x8*)&W2lo[aoff0];
        bf16x8 ah1 = *(const bf16x8*)&W2hi[aoff1];
        bf16x8 al1 = *(const bf16x8*)&W2lo[aoff1];
#pragma unroll
        for (int rt = 0; rt < 4; ++rt) {
            int boff = ((lane >> 4) * 64 + rt * 16 + (lane & 15)) * 8;
            bf16x8 bh = *(const bf16x8*)&xhi[boff];
            bf16x8 bl = *(const bf16x8*)&xlo[boff];
            acc[0][rt] = __builtin_amdgcn_mfma_f32_16x16x32_bf16(ah0, bh, acc[0][rt], 0, 0, 0);
            acc[0][rt] = __builtin_amdgcn_mfma_f32_16x16x32_bf16(ah0, bl, acc[0][rt], 0, 0, 0);
            acc[0][rt] = __builtin_amdgcn_mfma_f32_16x16x32_bf16(al0, bh, acc[0][rt], 0, 0, 0);
            acc[1][rt] = __builtin_amdgcn_mfma_f32_16x16x32_bf16(ah1, bh, acc[1][rt], 0, 0, 0);
            acc[1][rt] = __builtin_amdgcn_mfma_f32_16x16x32_bf16(ah1, bl, acc[1][rt], 0, 0, 0);
            acc[1][rt] = __builtin_amdgcn_mfma_f32_16x16x32_bf16(al1, bh, acc[1][rt], 0, 0, 0);
        }
        __syncthreads();
    }
    bool is_z = (j0 >= DI);   // j0 in {0,128,256,384,512,640}; DI=384=3*128
#pragma unroll
    for (int js = 0; js < 2; ++js) {
#pragma unroll
        for (int rt = 0; rt < 4; ++rt) {
            int rbase = r0 + rt * 16 + (lane & 15);
#pragma unroll
            for (int reg = 0; reg < 4; ++reg) {
                int j = jw + js * 64 + (lane >> 4) * 4 + reg;
                float o = acc[js][rt][reg] + bias2[j];
                if (is_z) o = __fdividef(o, 1.f + __expf(-o));
                xzT[j * RT + rbase] = o;
            }
        }
    }
}

// ---------------------------------------------------------------------------
// K3: skinny GEMM with fused causal depthwise conv (k=4) + silu in staging.
// 4-way K-split (R11-proven). grid (128,4), 512 thr.
__global__ __launch_bounds__(512) void xproj_conv_gemm(const float* __restrict__ xzT,
                                                       const float* __restrict__ conv_w,
                                                       const float* __restrict__ conv_b,
                                                       const float* __restrict__ aw,
                                                       float* __restrict__ xcT,
                                                       float* __restrict__ xdT) {
    __shared__ float Bs[32][64];
    int col0 = blockIdx.x * 64;
    int kbase = blockIdx.y * 96;
    int tid = threadIdx.x;
    int col = tid & 63, mg = tid >> 6;          // mg wave-uniform -> scalar A loads
    int mb = mg * 6;                             // rows mb..mb+5 (44..47 discarded)
    const float* ar[6];
#pragma unroll
    for (int m = 0; m < 6; ++m) ar[m] = aw + min(mb + m, 43) * DI + kbase;
    float acc[6] = {};
    int ks = tid >> 4, c4 = (tid & 15) * 4;
    bool atL0 = ((col0 & 1023) == 0) && (c4 == 0);   // conv zero-pad boundary
    for (int k0 = 0; k0 < 96; k0 += 32) {
        int dch = kbase + k0 + ks;
        const float* src = xzT + (size_t)dch * RT + col0 + c4;
        float4 cur = *(const float4*)src;
        float4 prev = make_float4(0.f, 0.f, 0.f, 0.f);
        if (!atL0) prev = *(const float4*)(src - 4);
        float4 w4 = *(const float4*)&conv_w[dch * 4];   // w0=x w1=y w2=z w3=w
        float bb = conv_b[dch];
        float v0 = bb + w4.w * cur.x + w4.z * prev.w + w4.y * prev.z + w4.x * prev.y;
        float v1 = bb + w4.w * cur.y + w4.z * cur.x  + w4.y * prev.w + w4.x * prev.z;
        float v2 = bb + w4.w * cur.z + w4.z * cur.y  + w4.y * cur.x  + w4.x * prev.w;
        float v3 = bb + w4.w * cur.w + w4.z * cur.z  + w4.y * cur.y  + w4.x * cur.x;
        float4 o;
        o.x = __fdividef(v0, 1.f + __expf(-v0));
        o.y = __fdividef(v1, 1.f + __expf(-v1));
        o.z = __fdividef(v2, 1.f + __expf(-v2));
        o.w = __fdividef(v3, 1.f + __expf(-v3));
        *(float4*)&Bs[ks][c4] = o;
        *(float4*)&xcT[(size_t)dch * RT + col0 + c4] = o;   // own channel range
        __syncthreads();
#pragma unroll
        for (int k = 0; k < 32; ++k) {
            float bv = Bs[k][col];
#pragma unroll
            for (int m = 0; m < 6; ++m)
                acc[m] = fmaf(ar[m][k0 + k], bv, acc[m]);
        }
        __syncthreads();
    }
#pragma unroll
    for (int m = 0; m < 6; ++m)
        if (mb + m < 44)
            atomicAdd(&xdT[(mb + m) * RT + col0 + col], acc[m]);
}

// ---------------------------------------------------------------------------
// K4a (R13): per-segment scan from h=0. Whole 64-step segment staged once;
// 2 barriers/block. R14: P/Hf packed into one float2 (single dwordx2 store).
// grid (15 seg, 24 dblk, 8 b), block 256.
__global__ __launch_bounds__(256) void scan_part1(const float* __restrict__ xdT,
                                                  const float* __restrict__ xcT,
                                                  const float* __restrict__ dtw,
                                                  const float* __restrict__ dtb,
                                                  const float* __restrict__ A_log,
                                                  float2* __restrict__ PH) {
    __shared__ float dt_s[16][68], g_s[16][68], B_s[16][68];
    __shared__ float dtr_s[12][68];
    __shared__ float dtw_s[192];
    __shared__ float dtb_s[16];
    int seg = blockIdx.x, d0 = blockIdx.y * 16, b = blockIdx.z;
    int row0 = b * LL + seg * SEGL;
    int tid = threadIdx.x;
    int lane = tid & 63;
    int n = lane & 15;
    int dl = ((tid >> 6) << 2) | (lane >> 4);
    int tdd = tid >> 4, ti = tid & 15;
    if (tid < 192) dtw_s[tid] = dtw[d0 * DT_RANK + tid];
    if (tid < 16)  dtb_s[tid] = dtb[d0 + tid];
    float a = -__expf(A_log[(d0 + dl) * NS + n]);
    // ---- stage entire segment (float4-wide)
    *(float4*)&B_s[tdd][ti * 4] = *(const float4*)&xdT[(12 + tdd) * RT + row0 + ti * 4];
    if (tid < 192)
        *(float4*)&dtr_s[tid >> 4][ti * 4] = *(const float4*)&xdT[(tid >> 4) * RT + row0 + ti * 4];
    float4 xv4 = *(const float4*)&xcT[(d0 + tdd) * RT + row0 + ti * 4];
    float xv[4] = {xv4.x, xv4.y, xv4.z, xv4.w};
    __syncthreads();
    // ---- dt compute: 4 cols per thread (same per-col fmaf order as before)
#pragma unroll
    for (int q = 0; q < 4; ++q) {
        int col = ti * 4 + q;
        float acc = dtb_s[tdd];
#pragma unroll
        for (int rr = 0; rr < DT_RANK; ++rr)
            acc = fmaf(dtr_s[rr][col], dtw_s[tdd * DT_RANK + rr], acc);
        float dtv = fmaxf(acc, 0.f) + __logf(1.f + __expf(-fabsf(acc)));
        dt_s[tdd][col] = dtv;
        g_s[tdd][col]  = dtv * xv[q];
    }
    __syncthreads();
    // ---- recurrence, barrier-free
    float h = 0.f, sdt = 0.f;
    for (int ch = 0; ch < 4; ++ch) {
        int c0 = ch * 16;
        float dv[16], gb[16];
#pragma unroll
        for (int q = 0; q < 4; ++q) {
            float4 d4 = *(const float4*)&dt_s[dl][c0 + q * 4];   // row-broadcast
            float4 g4 = *(const float4*)&g_s[dl][c0 + q * 4];
            float4 b4 = *(const float4*)&B_s[n][c0 + q * 4];
            dv[q * 4 + 0] = d4.x; dv[q * 4 + 1] = d4.y;
            dv[q * 4 + 2] = d4.z; dv[q * 4 + 3] = d4.w;
            gb[q * 4 + 0] = g4.x * b4.x; gb[q * 4 + 1] = g4.y * b4.y;
            gb[q * 4 + 2] = g4.z * b4.z; gb[q * 4 + 3] = g4.w * b4.w;
        }
        float eh[16];
#pragma unroll
        for (int i = 0; i < 16; ++i) eh[i] = __expf(dv[i] * a);
#pragma unroll
        for (int i = 0; i < 16; ++i) {
            sdt += dv[i];
            h = fmaf(eh[i], h, gb[i]);
        }
    }
    int idx = ((seg * BB + b) * DI + d0 + dl) * NS + n;
    PH[idx] = make_float2(__expf(a * sdt), h);
}

// ---------------------------------------------------------------------------
// K4b (R13): rescan each segment from folded h_init. Whole-segment staging;
// deferred select-butterfly (bitwise-identical). R14: h_init fold reads the
// packed float2 PH (one dwordx2/segment); all 4 chunks' xr/zr prefetched
// into registers before the first barrier (T14 - hide under staging+dt).
// grid (16 seg, 24 dblk, 8 b), block 256.
__global__ __launch_bounds__(256) void scan_part2(const float* __restrict__ xdT,
                                                  const float* __restrict__ xcT,
                                                  const float* __restrict__ zsT,
                                                  const float* __restrict__ dtw,
                                                  const float* __restrict__ dtb,
                                                  const float2* __restrict__ PH,
                                                  const float* __restrict__ A_log,
                                                  const float* __restrict__ Dp,
                                                  float* __restrict__ yT) {
    __shared__ float dt_s[16][68], g_s[16][68], B_s[16][68], C_s[16][68];
    __shared__ float dtr_s[12][68];
    __shared__ float dtw_s[192];
    __shared__ float dtb_s[16];
    int seg = blockIdx.x, d0 = blockIdx.y * 16, b = blockIdx.z;
    int row0 = b * LL + seg * SEGL;
    int tid = threadIdx.x;
    int lane = tid & 63;
    int n = lane & 15;
    int dl = ((tid >> 6) << 2) | (lane >> 4);
    int d = d0 + dl;
    int tdd = tid >> 4, ti = tid & 15;
    if (tid < 192) dtw_s[tid] = dtw[d0 * DT_RANK + tid];
    if (tid < 16)  dtb_s[tid] = dtb[d0 + tid];
    float a = -__expf(A_log[d * NS + n]);
    float Dpd = Dp[d];
    bool b3 = (n & 8) != 0, b2 = (n & 4) != 0, b1 = (n & 2) != 0, b0 = (n & 1) != 0;
    // ---- stage entire segment (float4-wide)
    *(float4*)&B_s[tdd][ti * 4] = *(const float4*)&xdT[(12 + tdd) * RT + row0 + ti * 4];
    *(float4*)&C_s[tdd][ti * 4] = *(const float4*)&xdT[(28 + tdd) * RT + row0 + ti * 4];
    if (tid < 192)
        *(float4*)&dtr_s[tid >> 4][ti * 4] = *(const float4*)&xdT[(tid >> 4) * RT + row0 + ti * 4];
    float4 xv4 = *(const float4*)&xcT[(d0 + tdd) * RT + row0 + ti * 4];
    float xv[4] = {xv4.x, xv4.y, xv4.z, xv4.w};
    // ---- prefetch epilogue operands for all 4 chunks (writer role (dl,n))
    float xr[4], zr[4];
#pragma unroll
    for (int ch = 0; ch < 4; ++ch) {
        xr[ch] = xcT[(size_t)d * RT + row0 + ch * 16 + n];
        zr[ch] = zsT[(size_t)d * RT + row0 + ch * 16 + n];
    }
    // h_init: fold earlier segments' summaries (packed dwordx2 loads)
    float h = 0.f;
    for (int s = 0; s < seg; ++s) {
        float2 ph = PH[((s * BB + b) * DI + d) * NS + n];
        h = fmaf(ph.x, h, ph.y);
    }
    __syncthreads();
    // ---- dt compute: 4 cols per thread
#pragma unroll
    for (int q = 0; q < 4; ++q) {
        int col = ti * 4 + q;
        float acc = dtb_s[tdd];
#pragma unroll
        for (int rr = 0; rr < DT_RANK; ++rr)
            acc = fmaf(dtr_s[rr][col], dtw_s[tdd * DT_RANK + rr], acc);
        float dtv = fmaxf(acc, 0.f) + __logf(1.f + __expf(-fabsf(acc)));
        dt_s[tdd][col] = dtv;
        g_s[tdd][col]  = dtv * xv[q];
    }
    __syncthreads();
    // ---- recurrence over 4 sub-chunks, barrier-free
    for (int ch = 0; ch < 4; ++ch) {
        int c0 = ch * 16;
        int r = row0 + c0;
        float dv[16], gb[16], cv[16];
#pragma unroll
        for (int q = 0; q < 4; ++q) {
            float4 d4 = *(const float4*)&dt_s[dl][c0 + q * 4];
            float4 g4 = *(const float4*)&g_s[dl][c0 + q * 4];
            float4 b4 = *(const float4*)&B_s[n][c0 + q * 4];
            float4 c4 = *(const float4*)&C_s[n][c0 + q * 4];
            dv[q * 4 + 0] = d4.x; dv[q * 4 + 1] = d4.y;
            dv[q * 4 + 2] = d4.z; dv[q * 4 + 3] = d4.w;
            gb[q * 4 + 0] = g4.x * b4.x; gb[q * 4 + 1] = g4.y * b4.y;
            gb[q * 4 + 2] = g4.z * b4.z; gb[q * 4 + 3] = g4.w * b4.w;
            cv[q * 4 + 0] = c4.x; cv[q * 4 + 1] = c4.y;
            cv[q * 4 + 2] = c4.z; cv[q * 4 + 3] = c4.w;
        }
        float eh[16];
#pragma unroll
        for (int i = 0; i < 16; ++i) eh[i] = __expf(dv[i] * a);
        // recurrence; w[i] = h_after_step_i * C[n][i]
        float w[16];
#pragma unroll
        for (int i = 0; i < 16; ++i) {
            h = fmaf(eh[i], h, gb[i]);
            w[i] = h * cv[i];
        }
        // deferred select-butterfly (R12-proven, bitwise-identical tree)
        float A8[8];
#pragma unroll
        for (int jj = 0; jj < 8; ++jj) {
            float snd = b3 ? w[jj] : w[jj + 8];
            float rcv = DPPF(snd, 0x140);
            A8[jj] = (b3 ? w[jj + 8] : w[jj]) + rcv;
        }
        float A4[4];
#pragma unroll
        for (int jj = 0; jj < 4; ++jj) {
            float snd = b2 ? A8[jj] : A8[jj + 4];
            float rcv = DPPF(snd, 0x141);
            A4[jj] = (b2 ? A8[jj + 4] : A8[jj]) + rcv;
        }
        float A2[2];
#pragma unroll
        for (int jj = 0; jj < 2; ++jj) {
            float s2 = b1 ? A4[jj] : A4[jj + 2];
            float rcv = DPPF(s2, 0x4E);
            A2[jj] = (b1 ? A4[jj + 2] : A4[jj]) + rcv;
        }
        float s1 = b0 ? A2[0] : A2[1];
        float rcv1 = DPPF(s1, 0xB1);
        float yacc = (b0 ? A2[1] : A2[0]) + rcv1;
        yT[(size_t)d * RT + r + n] = fmaf(xr[ch], Dpd, yacc) * zr[ch];
    }
}

// ---------------------------------------------------------------------------
// K5: out[b, c, l] = sum_d yT[d, row] * out_w[c, d]  via split-bf16 MFMA.
// R14: 64-k double staging — two 32-k tiles per barrier pair (barriers
// 24 -> 12/block; LDS 16 KB). MFMA consumption order unchanged (half 0
// then half 1, k ascending) -> bitwise-identical. grid (128, 3), 256 thr.
__global__ __launch_bounds__(256) void gemm_out(const float* __restrict__ yT,
                                                const unsigned short* __restrict__ owhi,
                                                const unsigned short* __restrict__ owlo,
                                                float* __restrict__ out) {
    __shared__ unsigned short yhi[2][2048];   // [half][kb][col][e] 8KB
    __shared__ unsigned short ylo[2][2048];
    int r0 = blockIdx.x * 64;
    int c0 = blockIdx.y * 64;
    int b  = r0 >> 10;
    int l0 = r0 & 1023;
    int tid = threadIdx.x;
    int lane = tid & 63;
    int wid = tid >> 6;          // wave id = staging kb
    int cw = c0 + wid * 16;
    const float* yb = yT + r0 + lane;      // staging col = lane
    f32x4 z4 = {0.f, 0.f, 0.f, 0.f};
    f32x4 acc[4] = {z4, z4, z4, z4};
    int arow = cw + (lane & 15);           // A fragment row (c)
    int akb  = (lane >> 4) * 8;            // A fragment k sub-block
    for (int ks = 0; ks < 6; ++ks) {
        int k0 = ks * 64;
        float v[2][8];
#pragma unroll
        for (int hh = 0; hh < 2; ++hh)
#pragma unroll
            for (int e = 0; e < 8; ++e)
                v[hh][e] = yb[(size_t)(k0 + hh * 32 + wid * 8 + e) * RT];
        union U8 { unsigned short u[8]; bf16x8 v8; } hv, lv;
#pragma unroll
        for (int hh = 0; hh < 2; ++hh) {
#pragma unroll
            for (int e = 0; e < 8; ++e) {
                unsigned short hb = f2bf(v[hh][e]);
                hv.u[e] = hb;
                lv.u[e] = f2bf(v[hh][e] - bf2f(hb));
            }
            *(bf16x8*)&yhi[hh][(wid * 64 + lane) * 8] = hv.v8;
            *(bf16x8*)&ylo[hh][(wid * 64 + lane) * 8] = lv.v8;
        }
        __syncthreads();
#pragma unroll
        for (int hh = 0; hh < 2; ++hh) {
            int aoff = arow * DI + k0 + hh * 32 + akb;
            bf16x8 ah = *(const bf16x8*)&owhi[aoff];
            bf16x8 al = *(const bf16x8*)&owlo[aoff];
#pragma unroll
            for (int rt = 0; rt < 4; ++rt) {
                int boff = ((lane >> 4) * 64 + rt * 16 + (lane & 15)) * 8;
                bf16x8 bh = *(const bf16x8*)&yhi[hh][boff];
                bf16x8 bl = *(const bf16x8*)&ylo[hh][boff];
                acc[rt] = __builtin_amdgcn_mfma_f32_16x16x32_bf16(ah, bh, acc[rt], 0, 0, 0);
                acc[rt] = __builtin_amdgcn_mfma_f32_16x16x32_bf16(ah, bl, acc[rt], 0, 0, 0);
                acc[rt] = __builtin_amdgcn_mfma_f32_16x16x32_bf16(al, bh, acc[rt], 0, 0, 0);
            }
        }
        __syncthreads();
    }
    float* ob = out + b * CC * LL;
#pragma unroll
    for (int rt = 0; rt < 4; ++rt) {
        int lbase = l0 + rt * 16 + (lane & 15);
#pragma unroll
        for (int reg = 0; reg < 4; ++reg) {
            int c = cw + (lane >> 4) * 4 + reg;
            ob[c * LL + lbase] = acc[rt][reg];
        }
    }
}

// ---------------------------------------------------------------------------
extern "C" void kernel_launch(void* const* d_in, const int* in_sizes, int n_in,
                              void* d_out, int out_size, void* d_ws, size_t ws_size,
                              hipStream_t stream) {
    const float* x         = (const float*)d_in[0];
    const float* proj_w    = (const float*)d_in[1];
    const float* proj_b    = (const float*)d_in[2];
    const float* in_proj_w = (const float*)d_in[3];
    const float* conv_w    = (const float*)d_in[4];
    const float* conv_b    = (const float*)d_in[5];
    const float* xproj_w   = (const float*)d_in[6];
    const float* dtproj_w  = (const float*)d_in[7];
    const float* dtproj_b  = (const float*)d_in[8];
    const float* A_log     = (const float*)d_in[9];
    const float* Dp        = (const float*)d_in[10];
    const float* out_w     = (const float*)d_in[11];
    float* out = (float*)d_out;

    float* ws    = (float*)d_ws;
    unsigned short* W2hi = (unsigned short*)ws;          // 147456 bf16 = 73728 f32 slots
    unsigned short* W2lo = (unsigned short*)(ws + 73728);
    float* bias2 = ws + 147456;           // 768
    float* xzT   = bias2 + 768;           // 768*8192 = 6291456 (x raw, z silu'd)
    float* xcT   = xzT + 6291456;         // 3145728
    float* yT    = xcT + 3145728;         // 3145728
    float* xdT   = yT + 3145728;          // 44*8192 = 360448 (0-11 dtr, 12-27 B, 28-43 C)
    float2* PH   = (float2*)(xdT + 360448);              // 786432 float2 (8B-aligned)
    unsigned short* owhi = (unsigned short*)(xdT + 360448 + 1572864);  // 73728 bf16
    unsigned short* owlo = (unsigned short*)(xdT + 360448 + 1572864 + 36864);
    float* zsT   = xzT + DI * RT;         // z half, silu applied by gemm_xz epilogue

    fuse_w_kernel<<<768, 192, 0, stream>>>(in_proj_w, proj_w, proj_b, out_w,
                                           W2hi, W2lo, owhi, owlo, bias2, xdT);
    gemm_xz<<<dim3(128, 6), 256, 0, stream>>>(x, W2hi, W2lo, bias2, xzT);
    xproj_conv_gemm<<<dim3(128, 4), 512, 0, stream>>>(xzT, conv_w, conv_b,
                                                      xproj_w, xcT, xdT);
    scan_part1<<<dim3(15, 24, 8), 256, 0, stream>>>(xdT, xcT, dtproj_w, dtproj_b,
                                                    A_log, PH);
    scan_part2<<<dim3(16, 24, 8), 256, 0, stream>>>(xdT, xcT, zsT, dtproj_w, dtproj_b,
                                                    PH, A_log, Dp, yT);
    gemm_out<<<dim3(128, 3), 256, 0, stream>>>(yT, owhi, owlo, out);
}